// Round 13
// baseline (463.806 us; speedup 1.0000x reference)
//
#include <hip/hip_runtime.h>
#include <hip/hip_fp16.h>

// GCN 3-layer forward: x[N,128] -> GCNConv(64) -> leaky -> GCNConv(32) -> leaky
// -> GCNConv(4) -> softmax.  N=100000, E=3200000.
// Round 13: (a) inter-layer activations h1/h2 stored fp16 (gather traffic halved;
// fg64 was L2-miss-path bound at 369MB FETCH). (b) edge-parallel lanes for narrow
// gathers: fg32 = 2 edges x 32 cols/wave-iter, fg4 = 16 edges x 4 cols (serial
// degree loop was the latency bottleneck). All accumulation stays f32.

#define BLK 256

// ---- Phase A: per-block LDS histogram over dst buckets (bucket = dst>>9) ----
__global__ __launch_bounds__(256) void k_hist(const int* __restrict__ dst,
                                              int* __restrict__ hist,
                                              int E, int CH, int NB) {
    __shared__ int h[256];
    int b = blockIdx.x, t = threadIdx.x;
    h[t] = 0;
    __syncthreads();
    int beg = b * CH, fin = min(E, beg + CH);
    for (int e = beg + t; e < fin; e += 256)
        atomicAdd(&h[dst[e] >> 9], 1);
    __syncthreads();
    if (t < NB) hist[t * 256 + b] = h[t];   // bucket-major layout
}

// ---- 3-kernel exclusive scan (n <= 512*256) ----
__global__ void k_scan1(const int* __restrict__ in, int* __restrict__ outv,
                        int* __restrict__ partials, int n) {
    __shared__ int sm[256];
    int i = blockIdx.x * 256 + threadIdx.x;
    int v = (i < n) ? in[i] : 0;
    sm[threadIdx.x] = v;
    __syncthreads();
    for (int off = 1; off < 256; off <<= 1) {
        int t = (threadIdx.x >= off) ? sm[threadIdx.x - off] : 0;
        __syncthreads();
        sm[threadIdx.x] += t;
        __syncthreads();
    }
    if (i < n) outv[i] = sm[threadIdx.x] - v;
    if (threadIdx.x == 255) partials[blockIdx.x] = sm[255];
}

__global__ void k_scan2(int* __restrict__ partials, int nb) {
    __shared__ int sm[512];
    int t = threadIdx.x;
    int v = (t < nb) ? partials[t] : 0;
    sm[t] = v;
    __syncthreads();
    for (int off = 1; off < 512; off <<= 1) {
        int x = (t >= off) ? sm[t - off] : 0;
        __syncthreads();
        sm[t] += x;
        __syncthreads();
    }
    if (t < nb) partials[t] = sm[t] - v;
}

__global__ void k_scan3(int* __restrict__ data, const int* __restrict__ partials, int n) {
    int i = blockIdx.x * 256 + threadIdx.x;
    if (i < n) data[i] += partials[i >> 8];
}

// ---- Phase C: scatter edges into bucket-sorted tmp ----
// record: x = (dlocal<<18) | src  (src < 2^18), y = w bits
__global__ __launch_bounds__(256) void k_bscatter(const int* __restrict__ src,
                                                  const int* __restrict__ dst,
                                                  const float* __restrict__ w,
                                                  const int* __restrict__ scanout,
                                                  int2* __restrict__ tmp,
                                                  int E, int CH, int NB) {
    __shared__ int cur[256];
    int b = blockIdx.x, t = threadIdx.x;
    if (t < NB) cur[t] = scanout[t * 256 + b];
    __syncthreads();
    int beg = b * CH, fin = min(E, beg + CH);
    for (int e = beg + t; e < fin; e += 256) {
        int d = dst[e];
        int q = d >> 9;
        int pos = atomicAdd(&cur[q], 1);             // LDS atomic
        tmp[pos] = make_int2(((d & 511) << 18) | src[e], __float_as_int(w[e]));
    }
}

// ---- Phase D: per-bucket CSR + fused dis = rsqrt(1 + sum_w) ----
__global__ __launch_bounds__(256) void k_bcsr(const int* __restrict__ scanout,
                                              const int2* __restrict__ tmp,
                                              int2* __restrict__ pack,
                                              int* __restrict__ row_ptr,
                                              float* __restrict__ dis,
                                              int n, int E, int NB) {
    __shared__ int cnt[512];
    __shared__ float wsum[512];
    __shared__ int psum[256];
    int q = blockIdx.x, t = threadIdx.x;
    int base = scanout[q * 256];
    int end  = (q == NB - 1) ? E : scanout[(q + 1) * 256];
    cnt[t] = 0; cnt[t + 256] = 0;
    wsum[t] = 0.f; wsum[t + 256] = 0.f;
    __syncthreads();
    for (int j = base + t; j < end; j += 256) {
        int2 r = tmp[j];
        int d = r.x >> 18;
        atomicAdd(&cnt[d], 1);
        atomicAdd(&wsum[d], __int_as_float(r.y));
    }
    __syncthreads();
    int a = cnt[2 * t], bb = cnt[2 * t + 1];
    psum[t] = a + bb;
    __syncthreads();
    for (int off = 1; off < 256; off <<= 1) {
        int v = (t >= off) ? psum[t - off] : 0;
        __syncthreads();
        psum[t] += v;
        __syncthreads();
    }
    int pex = psum[t] - (a + bb);
    __syncthreads();
    cnt[2 * t] = pex;                                // fill cursors
    cnt[2 * t + 1] = pex + a;
    int node0 = q * 512;
    if (node0 + 2 * t < n) {
        row_ptr[node0 + 2 * t] = base + pex;
        dis[node0 + 2 * t] = rsqrtf(1.f + wsum[2 * t]);
    }
    if (node0 + 2 * t + 1 < n) {
        row_ptr[node0 + 2 * t + 1] = base + pex + a;
        dis[node0 + 2 * t + 1] = rsqrtf(1.f + wsum[2 * t + 1]);
    }
    if (q == 0 && t == 0) row_ptr[n] = E;
    __syncthreads();
    for (int j = base + t; j < end; j += 256) {
        int2 r = tmp[j];
        int d = r.x >> 18;
        int pos = base + atomicAdd(&cnt[d], 1);      // LDS atomic
        pack[pos] = make_int2(r.x & 0x3FFFF, r.y);   // (src, w)
    }
}

// one wave per node: pack[j].y = dis[d] * w * dis[src]  (contiguous RMW, once)
__global__ __launch_bounds__(256) void k_norm(const int* __restrict__ rp,
                                              const float* __restrict__ dis,
                                              int2* __restrict__ pack, int n) {
    int node = blockIdx.x * 4 + (threadIdx.x >> 6);
    int lane = threadIdx.x & 63;
    if (node >= n) return;
    float dd = dis[node];
    int beg = rp[node], end = rp[node + 1];
    for (int j = beg + lane; j < end; j += 64) {
        int2 p = pack[j];
        p.y = __float_as_int(dd * __int_as_float(p.y) * dis[p.x]);
        pack[j] = p;
    }
}

__device__ __forceinline__ float leaky01(float v) {
    return v > 0.f ? v : 0.01f * v;
}
__device__ __forceinline__ float h2f(ushort u) {
    return __half2float(__ushort_as_half(u));
}
__device__ __forceinline__ ushort f2h(float f) {
    return __half_as_ushort(__float2half(f));
}

// layer-1 linear x[N,128] @ W1.T -> h1 fp16 [N,64]. 64-node tile, 4 thr/node.
__global__ __launch_bounds__(256) void k_linear1(
        const float* __restrict__ in, const float* __restrict__ W,
        ushort* __restrict__ outh, int n) {
    constexpr int FIN = 128, FOUT = 64, TM = 64, CPT = 16;
    __shared__ __align__(16) float Wt[FIN * FOUT];
    __shared__ __align__(16) float xst[TM * FIN];
    const int tid = threadIdx.x;
    const int nb = blockIdx.x * TM;

    for (int i = tid; i < FIN * FOUT; i += 256) {
        int c = i / FIN, k = i % FIN;
        Wt[k * FOUT + c] = W[i];
    }
    __syncthreads();
    for (int i4 = tid; i4 < TM * FIN / 4; i4 += 256) {
        int idx = i4 * 4;
        int r = idx / FIN, k0 = idx % FIN;
        if (nb + r < n) {
            float4 v = *(const float4*)&in[(size_t)(nb + r) * FIN + k0];
            xst[(k0 + 0) * TM + r] = v.x;
            xst[(k0 + 1) * TM + r] = v.y;
            xst[(k0 + 2) * TM + r] = v.z;
            xst[(k0 + 3) * TM + r] = v.w;
        }
    }
    __syncthreads();

    const int nl = tid >> 2;
    const int c0 = (tid & 3) * CPT;
    if (nb + nl >= n) return;

    float4 acc[CPT / 4];
#pragma unroll
    for (int j = 0; j < CPT / 4; ++j) acc[j] = make_float4(0.f, 0.f, 0.f, 0.f);
#pragma unroll 8
    for (int k = 0; k < FIN; ++k) {
        float xv = xst[k * TM + nl];
        const float4* wr = (const float4*)&Wt[k * FOUT + c0];
#pragma unroll
        for (int j = 0; j < CPT / 4; ++j) {
            float4 w4 = wr[j];
            acc[j].x += xv * w4.x; acc[j].y += xv * w4.y;
            acc[j].z += xv * w4.z; acc[j].w += xv * w4.w;
        }
    }
    uint* o = (uint*)&outh[(size_t)(nb + nl) * FOUT + c0];
#pragma unroll
    for (int j = 0; j < CPT / 4; ++j) {
        float4 a = acc[j];
        o[2 * j + 0] = (uint)f2h(a.x) | ((uint)f2h(a.y) << 16);
        o[2 * j + 1] = (uint)f2h(a.z) | ((uint)f2h(a.w) << 16);
    }
}

// layer-1 agg + leaky(+b1) + W2 matmul -> h2 fp16 [N,32]. One wave per node.
__global__ __launch_bounds__(256) void fgather64(
        const int* __restrict__ rp, const int2* __restrict__ pack,
        const float* __restrict__ dis, const ushort* __restrict__ h1h,
        const float* __restrict__ b1, const float* __restrict__ W2,   // [32][64]
        ushort* __restrict__ h2h, int n) {
    __shared__ float sW2t[64 * 33];    // [c][c2], padded
    __shared__ float sact[4][64];
    int tid = threadIdx.x;
    for (int i = tid; i < 2048; i += 256)
        sW2t[(i & 63) * 33 + (i >> 6)] = W2[i];
    int w = tid >> 6, l = tid & 63;
    int node = blockIdx.x * 4 + w;
    bool valid = node < n;
    float act = 0.f;
    if (valid) {
        float dd = dis[node];
        float acc = dd * dd * h2f(h1h[(size_t)node * 64 + l]);
        int beg = rp[node], end = rp[node + 1];
        int j = beg;
        for (; j + 8 <= end; j += 8) {
            int2 p[8];
            float hv[8];
#pragma unroll
            for (int u = 0; u < 8; ++u) p[u] = pack[j + u];
#pragma unroll
            for (int u = 0; u < 8; ++u) hv[u] = h2f(h1h[(size_t)p[u].x * 64 + l]);
#pragma unroll
            for (int u = 0; u < 8; ++u) acc += __int_as_float(p[u].y) * hv[u];
        }
        for (; j < end; ++j) {
            int2 p = pack[j];
            acc += __int_as_float(p.y) * h2f(h1h[(size_t)p.x * 64 + l]);
        }
        act = leaky01(acc + b1[l]);
    }
    sact[w][l] = act;
    __syncthreads();
    if (valid) {
        int c2 = l & 31, half = l >> 5;
        float s = 0.f;
#pragma unroll 8
        for (int cc = 0; cc < 32; ++cc) {
            int c = half * 32 + cc;
            s += sW2t[c * 33 + c2] * sact[w][c];
        }
        s += __shfl_xor(s, 32);
        if (l < 32) h2h[(size_t)node * 32 + c2] = f2h(s);
    }
}

// layer-2 agg + leaky(+b2) + W3 matmul -> h3 f32 [N,4].
// One wave per node: 2 edges x 32 cols per iteration.
__global__ __launch_bounds__(256) void fgather32(
        const int* __restrict__ rp, const int2* __restrict__ pack,
        const float* __restrict__ dis, const ushort* __restrict__ h2h,
        const float* __restrict__ b2, const float* __restrict__ W3,   // [4][32]
        float* __restrict__ h3out, int n) {
    __shared__ float sW3t[32 * 5];     // [c][c3], padded
    __shared__ float sact[4][32];
    int tid = threadIdx.x;
    if (tid < 128) sW3t[(tid & 31) * 5 + (tid >> 5)] = W3[tid];
    int w = tid >> 6, l = tid & 63;
    int es = l >> 5, g = l & 31;
    int node = blockIdx.x * 4 + w;
    bool valid = node < n;
    float acc = 0.f, dd = 0.f;
    if (valid) {
        dd = dis[node];
        int beg = rp[node], end = rp[node + 1];
        int j = beg + es;
        for (; j + 6 < end; j += 8) {        // 4 edges per half-wave in flight
            int2 p0 = pack[j], p1 = pack[j + 2], p2 = pack[j + 4], p3 = pack[j + 6];
            float h0 = h2f(h2h[(size_t)p0.x * 32 + g]);
            float h1 = h2f(h2h[(size_t)p1.x * 32 + g]);
            float h2v = h2f(h2h[(size_t)p2.x * 32 + g]);
            float h3v = h2f(h2h[(size_t)p3.x * 32 + g]);
            acc += __int_as_float(p0.y) * h0;
            acc += __int_as_float(p1.y) * h1;
            acc += __int_as_float(p2.y) * h2v;
            acc += __int_as_float(p3.y) * h3v;
        }
        for (; j < end; j += 2) {
            int2 p = pack[j];
            acc += __int_as_float(p.y) * h2f(h2h[(size_t)p.x * 32 + g]);
        }
    }
    acc += __shfl_xor(acc, 32);
    if (valid && l < 32) {
        acc += dd * dd * h2f(h2h[(size_t)node * 32 + g]);
        sact[w][g] = leaky01(acc + b2[g]);
    }
    __syncthreads();
    if (valid && l < 32) {
        int c3 = g & 3;
        float s = 0.f;
#pragma unroll
        for (int m = 0; m < 4; ++m) {
            int c = (g >> 2) + 8 * m;
            s += sW3t[c * 5 + c3] * sact[w][c];
        }
        s += __shfl_xor(s, 4, 32);
        s += __shfl_xor(s, 8, 32);
        s += __shfl_xor(s, 16, 32);
        if (g < 4) h3out[(size_t)node * 4 + g] = s;
    }
}

// layer-3 agg + b3 + softmax -> out[N,4].
// One wave per node: 16 edges x 4 cols per iteration.
__global__ __launch_bounds__(256) void fgather4(
        const int* __restrict__ rp, const int2* __restrict__ pack,
        const float* __restrict__ dis, const float* __restrict__ h3,
        const float* __restrict__ b3, float* __restrict__ out, int n) {
    int tid = threadIdx.x;
    int w = tid >> 6, l = tid & 63;
    int es = l >> 2, c = l & 3;
    int node = blockIdx.x * 4 + w;
    if (node >= n) return;
    float dd = dis[node];
    float acc = (es == 0) ? dd * dd * h3[(size_t)node * 4 + c] : 0.f;
    int beg = rp[node], end = rp[node + 1];
    for (int j = beg + es; j < end; j += 16) {
        int2 p = pack[j];
        acc += __int_as_float(p.y) * h3[(size_t)p.x * 4 + c];
    }
#pragma unroll
    for (int m = 4; m <= 32; m <<= 1) acc += __shfl_xor(acc, m);   // sum over es
    float v = acc + b3[c];
    float mx = fmaxf(v, __shfl_xor(v, 1, 4));
    mx = fmaxf(mx, __shfl_xor(mx, 2, 4));
    float e = expf(v - mx);
    float ssum = e + __shfl_xor(e, 1, 4);
    ssum += __shfl_xor(ssum, 2, 4);
    if (es == 0) out[(size_t)node * 4 + c] = e / ssum;
}

static inline int cdiv(long long a, int b) { return (int)((a + b - 1) / b); }

extern "C" void kernel_launch(void* const* d_in, const int* in_sizes, int n_in,
                              void* d_out, int out_size, void* d_ws, size_t ws_size,
                              hipStream_t stream) {
    const float* x   = (const float*)d_in[0];
    const int*   ei  = (const int*)d_in[1];
    const float* ew  = (const float*)d_in[2];
    const float* W1  = (const float*)d_in[3];
    const float* b1  = (const float*)d_in[4];
    const float* W2  = (const float*)d_in[5];
    const float* b2  = (const float*)d_in[6];
    const float* W3  = (const float*)d_in[7];
    const float* b3  = (const float*)d_in[8];
    float* out = (float*)d_out;

    const int N = in_sizes[0] / 128;
    const int E = in_sizes[2];
    const int* src = ei;
    const int* dst = ei + E;

    const int NB = (N + 511) >> 9;          // buckets of 512 nodes
    const int GB = 256;
    const int CH = cdiv(E, GB);
    const int n_scan = NB * GB;

    char* base = (char*)d_ws;
    auto alloc = [&](size_t bytes) {
        char* p = base;
        base += (bytes + 255) & ~(size_t)255;
        return p;
    };
    float* dis      = (float*)alloc((size_t)N * 4);
    int*   row_ptr  = (int*)  alloc(((size_t)N + 1) * 4);
    int*   hist     = (int*)  alloc((size_t)n_scan * 4);
    int*   scanout  = (int*)  alloc((size_t)n_scan * 4);
    int*   partials = (int*)  alloc(512 * 4);
    int2*  pack     = (int2*) alloc((size_t)E * 8);
    char*  regA     = alloc((size_t)N * 64 * 4);   // tmp -> h1h(fp16) -> h3(f32)
    char*  regB     = alloc((size_t)N * 64 * 4);   // h2h (fp16)
    int2*   tmp = (int2*)regA;
    ushort* h1h = (ushort*)regA;
    float*  h3  = (float*)regA;                    // reuses regA after h1 dead
    ushort* h2h = (ushort*)regB;

    // --- CSR build via bucket sort; dis fused into k_bcsr; norm premult once ---
    k_hist<<<GB, 256, 0, stream>>>(dst, hist, E, CH, NB);
    k_scan1<<<cdiv(n_scan, 256), 256, 0, stream>>>(hist, scanout, partials, n_scan);
    k_scan2<<<1, 512, 0, stream>>>(partials, cdiv(n_scan, 256));
    k_scan3<<<cdiv(n_scan, 256), 256, 0, stream>>>(scanout, partials, n_scan);
    k_bscatter<<<GB, 256, 0, stream>>>(src, dst, ew, scanout, tmp, E, CH, NB);
    k_bcsr<<<NB, 256, 0, stream>>>(scanout, tmp, pack, row_ptr, dis, N, E, NB);
    k_norm<<<cdiv(N, 4), 256, 0, stream>>>(row_ptr, dis, pack, N);

    // --- fused layers (h1/h2 fp16, h3 f32) ---
    k_linear1<<<cdiv(N, 64), 256, 0, stream>>>(x, W1, h1h, N);
    fgather64<<<cdiv(N, 4), 256, 0, stream>>>(row_ptr, pack, dis, h1h, b1, W2, h2h, N);
    fgather32<<<cdiv(N, 4), 256, 0, stream>>>(row_ptr, pack, dis, h2h, b2, W3, h3, N);
    fgather4<<<cdiv(N, 4), 256, 0, stream>>>(row_ptr, pack, dis, h3, b3, out, N);
}

// Round 14
// 410.016 us; speedup vs baseline: 1.1312x; 1.1312x over previous
//
#include <hip/hip_runtime.h>
#include <hip/hip_fp16.h>

// GCN 3-layer forward: x[N,128] -> GCNConv(64) -> leaky -> GCNConv(32) -> leaky
// -> GCNConv(4) -> softmax.  N=100000, E=3200000.
// Round 14: r13 showed fg64 is instruction/latency-bound (FETCH halved 369->166MB
// but dur 140->127 only). Rewrite gathers as wide multi-edge loads: fg64 = 4 edges
// per wave-instr (16-lane groups x ushort4), fg32 = 4 edges/instr (ushort2) x4
// unroll, fg4 reverted to r12 serial 4-lane-group form. f32 accum throughout.

#define BLK 256

// ---- Phase A: per-block LDS histogram over dst buckets (bucket = dst>>9) ----
__global__ __launch_bounds__(256) void k_hist(const int* __restrict__ dst,
                                              int* __restrict__ hist,
                                              int E, int CH, int NB) {
    __shared__ int h[256];
    int b = blockIdx.x, t = threadIdx.x;
    h[t] = 0;
    __syncthreads();
    int beg = b * CH, fin = min(E, beg + CH);
    for (int e = beg + t; e < fin; e += 256)
        atomicAdd(&h[dst[e] >> 9], 1);
    __syncthreads();
    if (t < NB) hist[t * 256 + b] = h[t];   // bucket-major layout
}

// ---- 3-kernel exclusive scan (n <= 512*256) ----
__global__ void k_scan1(const int* __restrict__ in, int* __restrict__ outv,
                        int* __restrict__ partials, int n) {
    __shared__ int sm[256];
    int i = blockIdx.x * 256 + threadIdx.x;
    int v = (i < n) ? in[i] : 0;
    sm[threadIdx.x] = v;
    __syncthreads();
    for (int off = 1; off < 256; off <<= 1) {
        int t = (threadIdx.x >= off) ? sm[threadIdx.x - off] : 0;
        __syncthreads();
        sm[threadIdx.x] += t;
        __syncthreads();
    }
    if (i < n) outv[i] = sm[threadIdx.x] - v;
    if (threadIdx.x == 255) partials[blockIdx.x] = sm[255];
}

__global__ void k_scan2(int* __restrict__ partials, int nb) {
    __shared__ int sm[512];
    int t = threadIdx.x;
    int v = (t < nb) ? partials[t] : 0;
    sm[t] = v;
    __syncthreads();
    for (int off = 1; off < 512; off <<= 1) {
        int x = (t >= off) ? sm[t - off] : 0;
        __syncthreads();
        sm[t] += x;
        __syncthreads();
    }
    if (t < nb) partials[t] = sm[t] - v;
}

__global__ void k_scan3(int* __restrict__ data, const int* __restrict__ partials, int n) {
    int i = blockIdx.x * 256 + threadIdx.x;
    if (i < n) data[i] += partials[i >> 8];
}

// ---- Phase C: scatter edges into bucket-sorted tmp ----
// record: x = (dlocal<<18) | src  (src < 2^18), y = w bits
__global__ __launch_bounds__(256) void k_bscatter(const int* __restrict__ src,
                                                  const int* __restrict__ dst,
                                                  const float* __restrict__ w,
                                                  const int* __restrict__ scanout,
                                                  int2* __restrict__ tmp,
                                                  int E, int CH, int NB) {
    __shared__ int cur[256];
    int b = blockIdx.x, t = threadIdx.x;
    if (t < NB) cur[t] = scanout[t * 256 + b];
    __syncthreads();
    int beg = b * CH, fin = min(E, beg + CH);
    for (int e = beg + t; e < fin; e += 256) {
        int d = dst[e];
        int q = d >> 9;
        int pos = atomicAdd(&cur[q], 1);             // LDS atomic
        tmp[pos] = make_int2(((d & 511) << 18) | src[e], __float_as_int(w[e]));
    }
}

// ---- Phase D: per-bucket CSR + fused dis = rsqrt(1 + sum_w) ----
__global__ __launch_bounds__(256) void k_bcsr(const int* __restrict__ scanout,
                                              const int2* __restrict__ tmp,
                                              int2* __restrict__ pack,
                                              int* __restrict__ row_ptr,
                                              float* __restrict__ dis,
                                              int n, int E, int NB) {
    __shared__ int cnt[512];
    __shared__ float wsum[512];
    __shared__ int psum[256];
    int q = blockIdx.x, t = threadIdx.x;
    int base = scanout[q * 256];
    int end  = (q == NB - 1) ? E : scanout[(q + 1) * 256];
    cnt[t] = 0; cnt[t + 256] = 0;
    wsum[t] = 0.f; wsum[t + 256] = 0.f;
    __syncthreads();
    for (int j = base + t; j < end; j += 256) {
        int2 r = tmp[j];
        int d = r.x >> 18;
        atomicAdd(&cnt[d], 1);
        atomicAdd(&wsum[d], __int_as_float(r.y));
    }
    __syncthreads();
    int a = cnt[2 * t], bb = cnt[2 * t + 1];
    psum[t] = a + bb;
    __syncthreads();
    for (int off = 1; off < 256; off <<= 1) {
        int v = (t >= off) ? psum[t - off] : 0;
        __syncthreads();
        psum[t] += v;
        __syncthreads();
    }
    int pex = psum[t] - (a + bb);
    __syncthreads();
    cnt[2 * t] = pex;                                // fill cursors
    cnt[2 * t + 1] = pex + a;
    int node0 = q * 512;
    if (node0 + 2 * t < n) {
        row_ptr[node0 + 2 * t] = base + pex;
        dis[node0 + 2 * t] = rsqrtf(1.f + wsum[2 * t]);
    }
    if (node0 + 2 * t + 1 < n) {
        row_ptr[node0 + 2 * t + 1] = base + pex + a;
        dis[node0 + 2 * t + 1] = rsqrtf(1.f + wsum[2 * t + 1]);
    }
    if (q == 0 && t == 0) row_ptr[n] = E;
    __syncthreads();
    for (int j = base + t; j < end; j += 256) {
        int2 r = tmp[j];
        int d = r.x >> 18;
        int pos = base + atomicAdd(&cnt[d], 1);      // LDS atomic
        pack[pos] = make_int2(r.x & 0x3FFFF, r.y);   // (src, w)
    }
}

// one wave per node: pack[j].y = dis[d] * w * dis[src]  (contiguous RMW, once)
__global__ __launch_bounds__(256) void k_norm(const int* __restrict__ rp,
                                              const float* __restrict__ dis,
                                              int2* __restrict__ pack, int n) {
    int node = blockIdx.x * 4 + (threadIdx.x >> 6);
    int lane = threadIdx.x & 63;
    if (node >= n) return;
    float dd = dis[node];
    int beg = rp[node], end = rp[node + 1];
    for (int j = beg + lane; j < end; j += 64) {
        int2 p = pack[j];
        p.y = __float_as_int(dd * __int_as_float(p.y) * dis[p.x]);
        pack[j] = p;
    }
}

__device__ __forceinline__ float leaky01(float v) {
    return v > 0.f ? v : 0.01f * v;
}
__device__ __forceinline__ float h2f(ushort u) {
    return __half2float(__ushort_as_half(u));
}
__device__ __forceinline__ ushort f2h(float f) {
    return __half_as_ushort(__float2half(f));
}
__device__ __forceinline__ float2 h2f2(uint u) {
    return make_float2(h2f((ushort)(u & 0xffff)), h2f((ushort)(u >> 16)));
}

// layer-1 linear x[N,128] @ W1.T -> h1 fp16 [N,64]. 64-node tile, 4 thr/node.
__global__ __launch_bounds__(256) void k_linear1(
        const float* __restrict__ in, const float* __restrict__ W,
        ushort* __restrict__ outh, int n) {
    constexpr int FIN = 128, FOUT = 64, TM = 64, CPT = 16;
    __shared__ __align__(16) float Wt[FIN * FOUT];
    __shared__ __align__(16) float xst[TM * FIN];
    const int tid = threadIdx.x;
    const int nb = blockIdx.x * TM;

    for (int i = tid; i < FIN * FOUT; i += 256) {
        int c = i / FIN, k = i % FIN;
        Wt[k * FOUT + c] = W[i];
    }
    __syncthreads();
    for (int i4 = tid; i4 < TM * FIN / 4; i4 += 256) {
        int idx = i4 * 4;
        int r = idx / FIN, k0 = idx % FIN;
        if (nb + r < n) {
            float4 v = *(const float4*)&in[(size_t)(nb + r) * FIN + k0];
            xst[(k0 + 0) * TM + r] = v.x;
            xst[(k0 + 1) * TM + r] = v.y;
            xst[(k0 + 2) * TM + r] = v.z;
            xst[(k0 + 3) * TM + r] = v.w;
        }
    }
    __syncthreads();

    const int nl = tid >> 2;
    const int c0 = (tid & 3) * CPT;
    if (nb + nl >= n) return;

    float4 acc[CPT / 4];
#pragma unroll
    for (int j = 0; j < CPT / 4; ++j) acc[j] = make_float4(0.f, 0.f, 0.f, 0.f);
#pragma unroll 8
    for (int k = 0; k < FIN; ++k) {
        float xv = xst[k * TM + nl];
        const float4* wr = (const float4*)&Wt[k * FOUT + c0];
#pragma unroll
        for (int j = 0; j < CPT / 4; ++j) {
            float4 w4 = wr[j];
            acc[j].x += xv * w4.x; acc[j].y += xv * w4.y;
            acc[j].z += xv * w4.z; acc[j].w += xv * w4.w;
        }
    }
    uint* o = (uint*)&outh[(size_t)(nb + nl) * FOUT + c0];
#pragma unroll
    for (int j = 0; j < CPT / 4; ++j) {
        float4 a = acc[j];
        o[2 * j + 0] = (uint)f2h(a.x) | ((uint)f2h(a.y) << 16);
        o[2 * j + 1] = (uint)f2h(a.z) | ((uint)f2h(a.w) << 16);
    }
}

// layer-1 agg + leaky(+b1) + W2 matmul -> h2 fp16 [N,32].  One wave per node;
// 4 edges per wave-instruction: 16-lane group es handles edge j+es, lane g=l&15
// loads ushort4 (cols 4g..4g+3).
__global__ __launch_bounds__(256) void fgather64(
        const int* __restrict__ rp, const int2* __restrict__ pack,
        const float* __restrict__ dis, const ushort* __restrict__ h1h,
        const float* __restrict__ b1, const float* __restrict__ W2,   // [32][64]
        ushort* __restrict__ h2h, int n) {
    __shared__ float sW2t[64 * 33];    // [c][c2], padded
    __shared__ float sact[4][64];
    int tid = threadIdx.x;
    for (int i = tid; i < 2048; i += 256)
        sW2t[(i & 63) * 33 + (i >> 6)] = W2[i];
    int w = tid >> 6, l = tid & 63;
    int es = l >> 4, g = l & 15;       // edge-set 0..3, col group
    int node = blockIdx.x * 4 + w;
    bool valid = node < n;
    float4 acc = make_float4(0.f, 0.f, 0.f, 0.f);
    if (valid) {
        int beg = rp[node], end = rp[node + 1];
        int j = beg;
        for (; j + 8 <= end; j += 8) {                 // 8 edges in flight
            int2 pa = pack[j + es];
            int2 pb = pack[j + 4 + es];
            uint2 ua = *(const uint2*)&h1h[(size_t)pa.x * 64 + 4 * g];
            uint2 ub = *(const uint2*)&h1h[(size_t)pb.x * 64 + 4 * g];
            float na = __int_as_float(pa.y), nb2 = __int_as_float(pb.y);
            float2 a0 = h2f2(ua.x), a1 = h2f2(ua.y);
            float2 b0 = h2f2(ub.x), b1v = h2f2(ub.y);
            acc.x += na * a0.x + nb2 * b0.x;
            acc.y += na * a0.y + nb2 * b0.y;
            acc.z += na * a1.x + nb2 * b1v.x;
            acc.w += na * a1.y + nb2 * b1v.y;
        }
        for (; j < end; j += 4) {
            if (j + es < end) {
                int2 p = pack[j + es];
                uint2 u = *(const uint2*)&h1h[(size_t)p.x * 64 + 4 * g];
                float nm = __int_as_float(p.y);
                float2 a0 = h2f2(u.x), a1 = h2f2(u.y);
                acc.x += nm * a0.x; acc.y += nm * a0.y;
                acc.z += nm * a1.x; acc.w += nm * a1.y;
            }
        }
        if (es == 0) {                                  // self-loop once
            float dd = dis[node];
            uint2 u = *(const uint2*)&h1h[(size_t)node * 64 + 4 * g];
            float2 a0 = h2f2(u.x), a1 = h2f2(u.y);
            float d2 = dd * dd;
            acc.x += d2 * a0.x; acc.y += d2 * a0.y;
            acc.z += d2 * a1.x; acc.w += d2 * a1.y;
        }
    }
    // combine edge-sets
    acc.x += __shfl_xor(acc.x, 16); acc.y += __shfl_xor(acc.y, 16);
    acc.z += __shfl_xor(acc.z, 16); acc.w += __shfl_xor(acc.w, 16);
    acc.x += __shfl_xor(acc.x, 32); acc.y += __shfl_xor(acc.y, 32);
    acc.z += __shfl_xor(acc.z, 32); acc.w += __shfl_xor(acc.w, 32);
    if (valid && es == 0) {
        sact[w][4 * g + 0] = leaky01(acc.x + b1[4 * g + 0]);
        sact[w][4 * g + 1] = leaky01(acc.y + b1[4 * g + 1]);
        sact[w][4 * g + 2] = leaky01(acc.z + b1[4 * g + 2]);
        sact[w][4 * g + 3] = leaky01(acc.w + b1[4 * g + 3]);
    }
    __syncthreads();
    if (valid) {
        int c2 = l & 31, half = l >> 5;
        float s = 0.f;
#pragma unroll 8
        for (int cc = 0; cc < 32; ++cc) {
            int c = half * 32 + cc;
            s += sW2t[c * 33 + c2] * sact[w][c];
        }
        s += __shfl_xor(s, 32);
        if (l < 32) h2h[(size_t)node * 32 + c2] = f2h(s);
    }
}

// layer-2 agg + leaky(+b2) + W3 matmul -> h3 f32 [N,4].  One wave per node;
// 4 edges/instr (16-lane groups x ushort2), unroll x4 = 16 edges in flight.
__global__ __launch_bounds__(256) void fgather32(
        const int* __restrict__ rp, const int2* __restrict__ pack,
        const float* __restrict__ dis, const ushort* __restrict__ h2h,
        const float* __restrict__ b2, const float* __restrict__ W3,   // [4][32]
        float* __restrict__ h3out, int n) {
    __shared__ float sW3t[32 * 5];     // [c][c3], padded
    __shared__ float sact[4][32];
    int tid = threadIdx.x;
    if (tid < 128) sW3t[(tid & 31) * 5 + (tid >> 5)] = W3[tid];
    int w = tid >> 6, l = tid & 63;
    int es = l >> 4, g = l & 15;       // lane cols (2g, 2g+1)
    int node = blockIdx.x * 4 + w;
    bool valid = node < n;
    float2 acc = make_float2(0.f, 0.f);
    if (valid) {
        int beg = rp[node], end = rp[node + 1];
        int j = beg;
        for (; j + 16 <= end; j += 16) {               // 16 edges in flight
            int2 p0 = pack[j + es];
            int2 p1 = pack[j + 4 + es];
            int2 p2 = pack[j + 8 + es];
            int2 p3 = pack[j + 12 + es];
            uint u0 = *(const uint*)&h2h[(size_t)p0.x * 32 + 2 * g];
            uint u1 = *(const uint*)&h2h[(size_t)p1.x * 32 + 2 * g];
            uint u2 = *(const uint*)&h2h[(size_t)p2.x * 32 + 2 * g];
            uint u3 = *(const uint*)&h2h[(size_t)p3.x * 32 + 2 * g];
            float2 a0 = h2f2(u0), a1 = h2f2(u1), a2 = h2f2(u2), a3 = h2f2(u3);
            float n0 = __int_as_float(p0.y), n1 = __int_as_float(p1.y);
            float n2 = __int_as_float(p2.y), n3 = __int_as_float(p3.y);
            acc.x += n0 * a0.x + n1 * a1.x + n2 * a2.x + n3 * a3.x;
            acc.y += n0 * a0.y + n1 * a1.y + n2 * a2.y + n3 * a3.y;
        }
        for (; j < end; j += 4) {
            if (j + es < end) {
                int2 p = pack[j + es];
                uint u = *(const uint*)&h2h[(size_t)p.x * 32 + 2 * g];
                float2 a = h2f2(u);
                float nm = __int_as_float(p.y);
                acc.x += nm * a.x; acc.y += nm * a.y;
            }
        }
        if (es == 0) {                                  // self-loop once
            float dd = dis[node];
            uint u = *(const uint*)&h2h[(size_t)node * 32 + 2 * g];
            float2 a = h2f2(u);
            float d2 = dd * dd;
            acc.x += d2 * a.x; acc.y += d2 * a.y;
        }
    }
    acc.x += __shfl_xor(acc.x, 16); acc.y += __shfl_xor(acc.y, 16);
    acc.x += __shfl_xor(acc.x, 32); acc.y += __shfl_xor(acc.y, 32);
    if (valid && es == 0) {
        sact[w][2 * g + 0] = leaky01(acc.x + b2[2 * g + 0]);
        sact[w][2 * g + 1] = leaky01(acc.y + b2[2 * g + 1]);
    }
    __syncthreads();
    if (valid && l < 32) {
        int g32 = l;
        int c3 = g32 & 3;
        float s = 0.f;
#pragma unroll
        for (int m = 0; m < 4; ++m) {
            int c = (g32 >> 2) + 8 * m;
            s += sW3t[c * 5 + c3] * sact[w][c];
        }
        s += __shfl_xor(s, 4, 32);
        s += __shfl_xor(s, 8, 32);
        s += __shfl_xor(s, 16, 32);
        if (g32 < 4) h3out[(size_t)node * 4 + g32] = s;
    }
}

// layer-3 agg + b3 + softmax -> out[N,4].  64 nodes/block, 4-lane group per node.
__global__ __launch_bounds__(256) void fgather4(
        const int* __restrict__ rp, const int2* __restrict__ pack,
        const float* __restrict__ dis, const float* __restrict__ h3,
        const float* __restrict__ b3, float* __restrict__ out, int n) {
    int tid = threadIdx.x;
    int node = blockIdx.x * 64 + (tid >> 2);
    int c = tid & 3;
    if (node >= n) return;
    float dd = dis[node];
    float acc = dd * dd * h3[(size_t)node * 4 + c];
    int beg = rp[node], end = rp[node + 1];
    int j = beg;
    for (; j + 8 <= end; j += 8) {
        int2 p[8];
        float hv[8];
#pragma unroll
        for (int u = 0; u < 8; ++u) p[u] = pack[j + u];
#pragma unroll
        for (int u = 0; u < 8; ++u) hv[u] = h3[(size_t)p[u].x * 4 + c];
#pragma unroll
        for (int u = 0; u < 8; ++u) acc += __int_as_float(p[u].y) * hv[u];
    }
    for (; j < end; ++j) {
        int2 p = pack[j];
        acc += __int_as_float(p.y) * h3[(size_t)p.x * 4 + c];
    }
    float v = acc + b3[c];
    float mx = fmaxf(v, __shfl_xor(v, 1, 4));
    mx = fmaxf(mx, __shfl_xor(mx, 2, 4));
    float e = expf(v - mx);
    float ssum = e + __shfl_xor(e, 1, 4);
    ssum += __shfl_xor(ssum, 2, 4);
    out[(size_t)node * 4 + c] = e / ssum;
}

static inline int cdiv(long long a, int b) { return (int)((a + b - 1) / b); }

extern "C" void kernel_launch(void* const* d_in, const int* in_sizes, int n_in,
                              void* d_out, int out_size, void* d_ws, size_t ws_size,
                              hipStream_t stream) {
    const float* x   = (const float*)d_in[0];
    const int*   ei  = (const int*)d_in[1];
    const float* ew  = (const float*)d_in[2];
    const float* W1  = (const float*)d_in[3];
    const float* b1  = (const float*)d_in[4];
    const float* W2  = (const float*)d_in[5];
    const float* b2  = (const float*)d_in[6];
    const float* W3  = (const float*)d_in[7];
    const float* b3  = (const float*)d_in[8];
    float* out = (float*)d_out;

    const int N = in_sizes[0] / 128;
    const int E = in_sizes[2];
    const int* src = ei;
    const int* dst = ei + E;

    const int NB = (N + 511) >> 9;          // buckets of 512 nodes
    const int GB = 256;
    const int CH = cdiv(E, GB);
    const int n_scan = NB * GB;

    char* base = (char*)d_ws;
    auto alloc = [&](size_t bytes) {
        char* p = base;
        base += (bytes + 255) & ~(size_t)255;
        return p;
    };
    float* dis      = (float*)alloc((size_t)N * 4);
    int*   row_ptr  = (int*)  alloc(((size_t)N + 1) * 4);
    int*   hist     = (int*)  alloc((size_t)n_scan * 4);
    int*   scanout  = (int*)  alloc((size_t)n_scan * 4);
    int*   partials = (int*)  alloc(512 * 4);
    int2*  pack     = (int2*) alloc((size_t)E * 8);
    char*  regA     = alloc((size_t)N * 64 * 4);   // tmp -> h1h(fp16) -> h3(f32)
    char*  regB     = alloc((size_t)N * 64 * 4);   // h2h (fp16)
    int2*   tmp = (int2*)regA;
    ushort* h1h = (ushort*)regA;
    float*  h3  = (float*)regA;                    // reuses regA after h1 dead
    ushort* h2h = (ushort*)regB;

    // --- CSR build via bucket sort; dis fused into k_bcsr; norm premult once ---
    k_hist<<<GB, 256, 0, stream>>>(dst, hist, E, CH, NB);
    k_scan1<<<cdiv(n_scan, 256), 256, 0, stream>>>(hist, scanout, partials, n_scan);
    k_scan2<<<1, 512, 0, stream>>>(partials, cdiv(n_scan, 256));
    k_scan3<<<cdiv(n_scan, 256), 256, 0, stream>>>(scanout, partials, n_scan);
    k_bscatter<<<GB, 256, 0, stream>>>(src, dst, ew, scanout, tmp, E, CH, NB);
    k_bcsr<<<NB, 256, 0, stream>>>(scanout, tmp, pack, row_ptr, dis, N, E, NB);
    k_norm<<<cdiv(N, 4), 256, 0, stream>>>(row_ptr, dis, pack, N);

    // --- fused layers (h1/h2 fp16, h3 f32) ---
    k_linear1<<<cdiv(N, 64), 256, 0, stream>>>(x, W1, h1h, N);
    fgather64<<<cdiv(N, 4), 256, 0, stream>>>(row_ptr, pack, dis, h1h, b1, W2, h2h, N);
    fgather32<<<cdiv(N, 4), 256, 0, stream>>>(row_ptr, pack, dis, h2h, b2, W3, h3, N);
    fgather4<<<cdiv(N, 64), 256, 0, stream>>>(row_ptr, pack, dis, h3, b3, out, N);
}

// Round 15
// 386.081 us; speedup vs baseline: 1.2013x; 1.0620x over previous
//
#include <hip/hip_runtime.h>
#include <hip/hip_fp16.h>

// GCN 3-layer forward: x[N,128] -> GCNConv(64) -> leaky -> GCNConv(32) -> leaky
// -> GCNConv(4) -> softmax.  N=100000, E=3200000.
// Round 15: r14 fg64 still issue-bound (FETCH flat 166MB, VALU 48%). Widen to the
// 16B/lane sweet spot: fg64 = 8-lane groups x uint4 = 8 edges/wave-instr; fg32 =
// 8-lane groups x uint2; fg4 = one float4 row per lane, 32-lane group per node,
// xor-tree reduce (kills the serial degree loop entirely).

#define BLK 256

// ---- Phase A: per-block LDS histogram over dst buckets (bucket = dst>>9) ----
__global__ __launch_bounds__(256) void k_hist(const int* __restrict__ dst,
                                              int* __restrict__ hist,
                                              int E, int CH, int NB) {
    __shared__ int h[256];
    int b = blockIdx.x, t = threadIdx.x;
    h[t] = 0;
    __syncthreads();
    int beg = b * CH, fin = min(E, beg + CH);
    for (int e = beg + t; e < fin; e += 256)
        atomicAdd(&h[dst[e] >> 9], 1);
    __syncthreads();
    if (t < NB) hist[t * 256 + b] = h[t];   // bucket-major layout
}

// ---- 3-kernel exclusive scan (n <= 512*256) ----
__global__ void k_scan1(const int* __restrict__ in, int* __restrict__ outv,
                        int* __restrict__ partials, int n) {
    __shared__ int sm[256];
    int i = blockIdx.x * 256 + threadIdx.x;
    int v = (i < n) ? in[i] : 0;
    sm[threadIdx.x] = v;
    __syncthreads();
    for (int off = 1; off < 256; off <<= 1) {
        int t = (threadIdx.x >= off) ? sm[threadIdx.x - off] : 0;
        __syncthreads();
        sm[threadIdx.x] += t;
        __syncthreads();
    }
    if (i < n) outv[i] = sm[threadIdx.x] - v;
    if (threadIdx.x == 255) partials[blockIdx.x] = sm[255];
}

__global__ void k_scan2(int* __restrict__ partials, int nb) {
    __shared__ int sm[512];
    int t = threadIdx.x;
    int v = (t < nb) ? partials[t] : 0;
    sm[t] = v;
    __syncthreads();
    for (int off = 1; off < 512; off <<= 1) {
        int x = (t >= off) ? sm[t - off] : 0;
        __syncthreads();
        sm[t] += x;
        __syncthreads();
    }
    if (t < nb) partials[t] = sm[t] - v;
}

__global__ void k_scan3(int* __restrict__ data, const int* __restrict__ partials, int n) {
    int i = blockIdx.x * 256 + threadIdx.x;
    if (i < n) data[i] += partials[i >> 8];
}

// ---- Phase C: scatter edges into bucket-sorted tmp ----
// record: x = (dlocal<<18) | src  (src < 2^18), y = w bits
__global__ __launch_bounds__(256) void k_bscatter(const int* __restrict__ src,
                                                  const int* __restrict__ dst,
                                                  const float* __restrict__ w,
                                                  const int* __restrict__ scanout,
                                                  int2* __restrict__ tmp,
                                                  int E, int CH, int NB) {
    __shared__ int cur[256];
    int b = blockIdx.x, t = threadIdx.x;
    if (t < NB) cur[t] = scanout[t * 256 + b];
    __syncthreads();
    int beg = b * CH, fin = min(E, beg + CH);
    for (int e = beg + t; e < fin; e += 256) {
        int d = dst[e];
        int q = d >> 9;
        int pos = atomicAdd(&cur[q], 1);             // LDS atomic
        tmp[pos] = make_int2(((d & 511) << 18) | src[e], __float_as_int(w[e]));
    }
}

// ---- Phase D: per-bucket CSR + fused dis = rsqrt(1 + sum_w) ----
__global__ __launch_bounds__(256) void k_bcsr(const int* __restrict__ scanout,
                                              const int2* __restrict__ tmp,
                                              int2* __restrict__ pack,
                                              int* __restrict__ row_ptr,
                                              float* __restrict__ dis,
                                              int n, int E, int NB) {
    __shared__ int cnt[512];
    __shared__ float wsum[512];
    __shared__ int psum[256];
    int q = blockIdx.x, t = threadIdx.x;
    int base = scanout[q * 256];
    int end  = (q == NB - 1) ? E : scanout[(q + 1) * 256];
    cnt[t] = 0; cnt[t + 256] = 0;
    wsum[t] = 0.f; wsum[t + 256] = 0.f;
    __syncthreads();
    for (int j = base + t; j < end; j += 256) {
        int2 r = tmp[j];
        int d = r.x >> 18;
        atomicAdd(&cnt[d], 1);
        atomicAdd(&wsum[d], __int_as_float(r.y));
    }
    __syncthreads();
    int a = cnt[2 * t], bb = cnt[2 * t + 1];
    psum[t] = a + bb;
    __syncthreads();
    for (int off = 1; off < 256; off <<= 1) {
        int v = (t >= off) ? psum[t - off] : 0;
        __syncthreads();
        psum[t] += v;
        __syncthreads();
    }
    int pex = psum[t] - (a + bb);
    __syncthreads();
    cnt[2 * t] = pex;                                // fill cursors
    cnt[2 * t + 1] = pex + a;
    int node0 = q * 512;
    if (node0 + 2 * t < n) {
        row_ptr[node0 + 2 * t] = base + pex;
        dis[node0 + 2 * t] = rsqrtf(1.f + wsum[2 * t]);
    }
    if (node0 + 2 * t + 1 < n) {
        row_ptr[node0 + 2 * t + 1] = base + pex + a;
        dis[node0 + 2 * t + 1] = rsqrtf(1.f + wsum[2 * t + 1]);
    }
    if (q == 0 && t == 0) row_ptr[n] = E;
    __syncthreads();
    for (int j = base + t; j < end; j += 256) {
        int2 r = tmp[j];
        int d = r.x >> 18;
        int pos = base + atomicAdd(&cnt[d], 1);      // LDS atomic
        pack[pos] = make_int2(r.x & 0x3FFFF, r.y);   // (src, w)
    }
}

// one wave per node: pack[j].y = dis[d] * w * dis[src]  (contiguous RMW, once)
__global__ __launch_bounds__(256) void k_norm(const int* __restrict__ rp,
                                              const float* __restrict__ dis,
                                              int2* __restrict__ pack, int n) {
    int node = blockIdx.x * 4 + (threadIdx.x >> 6);
    int lane = threadIdx.x & 63;
    if (node >= n) return;
    float dd = dis[node];
    int beg = rp[node], end = rp[node + 1];
    for (int j = beg + lane; j < end; j += 64) {
        int2 p = pack[j];
        p.y = __float_as_int(dd * __int_as_float(p.y) * dis[p.x]);
        pack[j] = p;
    }
}

__device__ __forceinline__ float leaky01(float v) {
    return v > 0.f ? v : 0.01f * v;
}
__device__ __forceinline__ float h2f(ushort u) {
    return __half2float(__ushort_as_half(u));
}
__device__ __forceinline__ ushort f2h(float f) {
    return __half_as_ushort(__float2half(f));
}
__device__ __forceinline__ float2 h2f2(uint u) {
    return make_float2(h2f((ushort)(u & 0xffff)), h2f((ushort)(u >> 16)));
}

// layer-1 linear x[N,128] @ W1.T -> h1 fp16 [N,64]. 64-node tile, 4 thr/node.
__global__ __launch_bounds__(256) void k_linear1(
        const float* __restrict__ in, const float* __restrict__ W,
        ushort* __restrict__ outh, int n) {
    constexpr int FIN = 128, FOUT = 64, TM = 64, CPT = 16;
    __shared__ __align__(16) float Wt[FIN * FOUT];
    __shared__ __align__(16) float xst[TM * FIN];
    const int tid = threadIdx.x;
    const int nb = blockIdx.x * TM;

    for (int i = tid; i < FIN * FOUT; i += 256) {
        int c = i / FIN, k = i % FIN;
        Wt[k * FOUT + c] = W[i];
    }
    __syncthreads();
    for (int i4 = tid; i4 < TM * FIN / 4; i4 += 256) {
        int idx = i4 * 4;
        int r = idx / FIN, k0 = idx % FIN;
        if (nb + r < n) {
            float4 v = *(const float4*)&in[(size_t)(nb + r) * FIN + k0];
            xst[(k0 + 0) * TM + r] = v.x;
            xst[(k0 + 1) * TM + r] = v.y;
            xst[(k0 + 2) * TM + r] = v.z;
            xst[(k0 + 3) * TM + r] = v.w;
        }
    }
    __syncthreads();

    const int nl = tid >> 2;
    const int c0 = (tid & 3) * CPT;
    if (nb + nl >= n) return;

    float4 acc[CPT / 4];
#pragma unroll
    for (int j = 0; j < CPT / 4; ++j) acc[j] = make_float4(0.f, 0.f, 0.f, 0.f);
#pragma unroll 8
    for (int k = 0; k < FIN; ++k) {
        float xv = xst[k * TM + nl];
        const float4* wr = (const float4*)&Wt[k * FOUT + c0];
#pragma unroll
        for (int j = 0; j < CPT / 4; ++j) {
            float4 w4 = wr[j];
            acc[j].x += xv * w4.x; acc[j].y += xv * w4.y;
            acc[j].z += xv * w4.z; acc[j].w += xv * w4.w;
        }
    }
    uint* o = (uint*)&outh[(size_t)(nb + nl) * FOUT + c0];
#pragma unroll
    for (int j = 0; j < CPT / 4; ++j) {
        float4 a = acc[j];
        o[2 * j + 0] = (uint)f2h(a.x) | ((uint)f2h(a.y) << 16);
        o[2 * j + 1] = (uint)f2h(a.z) | ((uint)f2h(a.w) << 16);
    }
}

// layer-1 agg + leaky(+b1) + W2 matmul -> h2 fp16 [N,32].  One wave per node;
// 8 edges per wave-instruction: 8-lane group es, lane g=l&7 loads uint4
// (16B = cols 8g..8g+7 of the fp16 row).
__global__ __launch_bounds__(256) void fgather64(
        const int* __restrict__ rp, const int2* __restrict__ pack,
        const float* __restrict__ dis, const ushort* __restrict__ h1h,
        const float* __restrict__ b1, const float* __restrict__ W2,   // [32][64]
        ushort* __restrict__ h2h, int n) {
    __shared__ float sW2t[64 * 33];    // [c][c2], padded
    __shared__ float sact[4][64];
    int tid = threadIdx.x;
    for (int i = tid; i < 2048; i += 256)
        sW2t[(i & 63) * 33 + (i >> 6)] = W2[i];
    int w = tid >> 6, l = tid & 63;
    int es = l >> 3, g = l & 7;        // edge-set 0..7, col group (cols 8g..8g+7)
    int node = blockIdx.x * 4 + w;
    bool valid = node < n;
    float acc[8] = {0.f, 0.f, 0.f, 0.f, 0.f, 0.f, 0.f, 0.f};
    if (valid) {
        int beg = rp[node], end = rp[node + 1];
        int j = beg;
        for (; j + 16 <= end; j += 16) {               // 16 edges in flight
            int2 pa = pack[j + es];
            int2 pb = pack[j + 8 + es];
            uint4 ua = *(const uint4*)&h1h[(size_t)pa.x * 64 + 8 * g];
            uint4 ub = *(const uint4*)&h1h[(size_t)pb.x * 64 + 8 * g];
            float na = __int_as_float(pa.y), nb2 = __int_as_float(pb.y);
            float2 v;
            v = h2f2(ua.x); acc[0] += na * v.x;  acc[1] += na * v.y;
            v = h2f2(ua.y); acc[2] += na * v.x;  acc[3] += na * v.y;
            v = h2f2(ua.z); acc[4] += na * v.x;  acc[5] += na * v.y;
            v = h2f2(ua.w); acc[6] += na * v.x;  acc[7] += na * v.y;
            v = h2f2(ub.x); acc[0] += nb2 * v.x; acc[1] += nb2 * v.y;
            v = h2f2(ub.y); acc[2] += nb2 * v.x; acc[3] += nb2 * v.y;
            v = h2f2(ub.z); acc[4] += nb2 * v.x; acc[5] += nb2 * v.y;
            v = h2f2(ub.w); acc[6] += nb2 * v.x; acc[7] += nb2 * v.y;
        }
        for (; j < end; j += 8) {
            if (j + es < end) {
                int2 p = pack[j + es];
                uint4 u = *(const uint4*)&h1h[(size_t)p.x * 64 + 8 * g];
                float nm = __int_as_float(p.y);
                float2 v;
                v = h2f2(u.x); acc[0] += nm * v.x; acc[1] += nm * v.y;
                v = h2f2(u.y); acc[2] += nm * v.x; acc[3] += nm * v.y;
                v = h2f2(u.z); acc[4] += nm * v.x; acc[5] += nm * v.y;
                v = h2f2(u.w); acc[6] += nm * v.x; acc[7] += nm * v.y;
            }
        }
        // combine the 8 edge-sets
#pragma unroll
        for (int u = 0; u < 8; ++u) {
            acc[u] += __shfl_xor(acc[u], 8);
            acc[u] += __shfl_xor(acc[u], 16);
            acc[u] += __shfl_xor(acc[u], 32);
        }
        if (es == 0) {                                  // self-loop + bias
            float dd = dis[node], d2 = dd * dd;
            uint4 u = *(const uint4*)&h1h[(size_t)node * 64 + 8 * g];
            float2 v;
            v = h2f2(u.x); acc[0] += d2 * v.x; acc[1] += d2 * v.y;
            v = h2f2(u.y); acc[2] += d2 * v.x; acc[3] += d2 * v.y;
            v = h2f2(u.z); acc[4] += d2 * v.x; acc[5] += d2 * v.y;
            v = h2f2(u.w); acc[6] += d2 * v.x; acc[7] += d2 * v.y;
#pragma unroll
            for (int u2 = 0; u2 < 8; ++u2)
                sact[w][8 * g + u2] = leaky01(acc[u2] + b1[8 * g + u2]);
        }
    }
    __syncthreads();
    if (valid) {
        int c2 = l & 31, half = l >> 5;
        float s = 0.f;
#pragma unroll 8
        for (int cc = 0; cc < 32; ++cc) {
            int c = half * 32 + cc;
            s += sW2t[c * 33 + c2] * sact[w][c];
        }
        s += __shfl_xor(s, 32);
        if (l < 32) h2h[(size_t)node * 32 + c2] = f2h(s);
    }
}

// layer-2 agg + leaky(+b2) + W3 matmul -> h3 f32 [N,4].  One wave per node;
// 8 edges/instr (8-lane groups x uint2 = cols 4g..4g+3), x2 unroll.
__global__ __launch_bounds__(256) void fgather32(
        const int* __restrict__ rp, const int2* __restrict__ pack,
        const float* __restrict__ dis, const ushort* __restrict__ h2h,
        const float* __restrict__ b2, const float* __restrict__ W3,   // [4][32]
        float* __restrict__ h3out, int n) {
    __shared__ float sW3t[32 * 5];     // [c][c3], padded
    __shared__ float sact[4][32];
    int tid = threadIdx.x;
    if (tid < 128) sW3t[(tid & 31) * 5 + (tid >> 5)] = W3[tid];
    int w = tid >> 6, l = tid & 63;
    int es = l >> 3, g = l & 7;        // cols 4g..4g+3
    int node = blockIdx.x * 4 + w;
    bool valid = node < n;
    float acc[4] = {0.f, 0.f, 0.f, 0.f};
    if (valid) {
        int beg = rp[node], end = rp[node + 1];
        int j = beg;
        for (; j + 16 <= end; j += 16) {               // 16 edges in flight
            int2 pa = pack[j + es];
            int2 pb = pack[j + 8 + es];
            uint2 ua = *(const uint2*)&h2h[(size_t)pa.x * 32 + 4 * g];
            uint2 ub = *(const uint2*)&h2h[(size_t)pb.x * 32 + 4 * g];
            float na = __int_as_float(pa.y), nb2 = __int_as_float(pb.y);
            float2 v;
            v = h2f2(ua.x); acc[0] += na * v.x;  acc[1] += na * v.y;
            v = h2f2(ua.y); acc[2] += na * v.x;  acc[3] += na * v.y;
            v = h2f2(ub.x); acc[0] += nb2 * v.x; acc[1] += nb2 * v.y;
            v = h2f2(ub.y); acc[2] += nb2 * v.x; acc[3] += nb2 * v.y;
        }
        for (; j < end; j += 8) {
            if (j + es < end) {
                int2 p = pack[j + es];
                uint2 u = *(const uint2*)&h2h[(size_t)p.x * 32 + 4 * g];
                float nm = __int_as_float(p.y);
                float2 v;
                v = h2f2(u.x); acc[0] += nm * v.x; acc[1] += nm * v.y;
                v = h2f2(u.y); acc[2] += nm * v.x; acc[3] += nm * v.y;
            }
        }
#pragma unroll
        for (int u = 0; u < 4; ++u) {
            acc[u] += __shfl_xor(acc[u], 8);
            acc[u] += __shfl_xor(acc[u], 16);
            acc[u] += __shfl_xor(acc[u], 32);
        }
        if (es == 0) {
            float dd = dis[node], d2 = dd * dd;
            uint2 u = *(const uint2*)&h2h[(size_t)node * 32 + 4 * g];
            float2 v;
            v = h2f2(u.x); acc[0] += d2 * v.x; acc[1] += d2 * v.y;
            v = h2f2(u.y); acc[2] += d2 * v.x; acc[3] += d2 * v.y;
#pragma unroll
            for (int u2 = 0; u2 < 4; ++u2)
                sact[w][4 * g + u2] = leaky01(acc[u2] + b2[4 * g + u2]);
        }
    }
    __syncthreads();
    if (valid && l < 32) {
        int c3 = l & 3;
        float s = 0.f;
#pragma unroll
        for (int m = 0; m < 4; ++m) {
            int c = (l >> 2) + 8 * m;
            s += sW3t[c * 5 + c3] * sact[w][c];
        }
        s += __shfl_xor(s, 4, 32);
        s += __shfl_xor(s, 8, 32);
        s += __shfl_xor(s, 16, 32);
        if (l < 4) h3out[(size_t)node * 4 + l] = s;
    }
}

// layer-3 agg + b3 + softmax -> out[N,4].  32-lane group per node; lane j owns
// edge beg+j and loads the full 16B h3 row as float4; xor-tree reduce.
__global__ __launch_bounds__(256) void fgather4(
        const int* __restrict__ rp, const int2* __restrict__ pack,
        const float* __restrict__ dis, const float* __restrict__ h3,
        const float* __restrict__ b3, float* __restrict__ out, int n) {
    int tid = threadIdx.x;
    int node = blockIdx.x * 8 + (tid >> 5);
    int l32 = tid & 31;
    if (node >= n) return;
    int beg = rp[node], end = rp[node + 1];
    float4 acc = make_float4(0.f, 0.f, 0.f, 0.f);
    for (int j = beg + l32; j < end; j += 32) {
        int2 p = pack[j];
        float4 hr = *(const float4*)&h3[(size_t)p.x * 4];
        float nm = __int_as_float(p.y);
        acc.x += nm * hr.x; acc.y += nm * hr.y;
        acc.z += nm * hr.z; acc.w += nm * hr.w;
    }
#pragma unroll
    for (int off = 1; off <= 16; off <<= 1) {
        acc.x += __shfl_xor(acc.x, off, 32);
        acc.y += __shfl_xor(acc.y, off, 32);
        acc.z += __shfl_xor(acc.z, off, 32);
        acc.w += __shfl_xor(acc.w, off, 32);
    }
    if (l32 == 0) {
        float dd = dis[node], d2 = dd * dd;
        float4 hr = *(const float4*)&h3[(size_t)node * 4];
        float v0 = acc.x + d2 * hr.x + b3[0];
        float v1 = acc.y + d2 * hr.y + b3[1];
        float v2 = acc.z + d2 * hr.z + b3[2];
        float v3 = acc.w + d2 * hr.w + b3[3];
        float m = fmaxf(fmaxf(v0, v1), fmaxf(v2, v3));
        float e0 = expf(v0 - m), e1 = expf(v1 - m);
        float e2 = expf(v2 - m), e3 = expf(v3 - m);
        float inv = 1.f / (e0 + e1 + e2 + e3);
        *(float4*)&out[(size_t)node * 4] =
            make_float4(e0 * inv, e1 * inv, e2 * inv, e3 * inv);
    }
}

static inline int cdiv(long long a, int b) { return (int)((a + b - 1) / b); }

extern "C" void kernel_launch(void* const* d_in, const int* in_sizes, int n_in,
                              void* d_out, int out_size, void* d_ws, size_t ws_size,
                              hipStream_t stream) {
    const float* x   = (const float*)d_in[0];
    const int*   ei  = (const int*)d_in[1];
    const float* ew  = (const float*)d_in[2];
    const float* W1  = (const float*)d_in[3];
    const float* b1  = (const float*)d_in[4];
    const float* W2  = (const float*)d_in[5];
    const float* b2  = (const float*)d_in[6];
    const float* W3  = (const float*)d_in[7];
    const float* b3  = (const float*)d_in[8];
    float* out = (float*)d_out;

    const int N = in_sizes[0] / 128;
    const int E = in_sizes[2];
    const int* src = ei;
    const int* dst = ei + E;

    const int NB = (N + 511) >> 9;          // buckets of 512 nodes
    const int GB = 256;
    const int CH = cdiv(E, GB);
    const int n_scan = NB * GB;

    char* base = (char*)d_ws;
    auto alloc = [&](size_t bytes) {
        char* p = base;
        base += (bytes + 255) & ~(size_t)255;
        return p;
    };
    float* dis      = (float*)alloc((size_t)N * 4);
    int*   row_ptr  = (int*)  alloc(((size_t)N + 1) * 4);
    int*   hist     = (int*)  alloc((size_t)n_scan * 4);
    int*   scanout  = (int*)  alloc((size_t)n_scan * 4);
    int*   partials = (int*)  alloc(512 * 4);
    int2*  pack     = (int2*) alloc((size_t)E * 8);
    char*  regA     = alloc((size_t)N * 64 * 4);   // tmp -> h1h(fp16) -> h3(f32)
    char*  regB     = alloc((size_t)N * 64 * 4);   // h2h (fp16)
    int2*   tmp = (int2*)regA;
    ushort* h1h = (ushort*)regA;
    float*  h3  = (float*)regA;                    // reuses regA after h1 dead
    ushort* h2h = (ushort*)regB;

    // --- CSR build via bucket sort; dis fused into k_bcsr; norm premult once ---
    k_hist<<<GB, 256, 0, stream>>>(dst, hist, E, CH, NB);
    k_scan1<<<cdiv(n_scan, 256), 256, 0, stream>>>(hist, scanout, partials, n_scan);
    k_scan2<<<1, 512, 0, stream>>>(partials, cdiv(n_scan, 256));
    k_scan3<<<cdiv(n_scan, 256), 256, 0, stream>>>(scanout, partials, n_scan);
    k_bscatter<<<GB, 256, 0, stream>>>(src, dst, ew, scanout, tmp, E, CH, NB);
    k_bcsr<<<NB, 256, 0, stream>>>(scanout, tmp, pack, row_ptr, dis, N, E, NB);
    k_norm<<<cdiv(N, 4), 256, 0, stream>>>(row_ptr, dis, pack, N);

    // --- fused layers (h1/h2 fp16, h3 f32) ---
    k_linear1<<<cdiv(N, 64), 256, 0, stream>>>(x, W1, h1h, N);
    fgather64<<<cdiv(N, 4), 256, 0, stream>>>(row_ptr, pack, dis, h1h, b1, W2, h2h, N);
    fgather32<<<cdiv(N, 4), 256, 0, stream>>>(row_ptr, pack, dis, h2h, b2, W3, h3, N);
    fgather4<<<cdiv(N, 8), 256, 0, stream>>>(row_ptr, pack, dis, h3, b3, out, N);
}

// Round 16
// 351.446 us; speedup vs baseline: 1.3197x; 1.0985x over previous
//
#include <hip/hip_runtime.h>
#include <hip/hip_fp16.h>

// GCN 3-layer forward: x[N,128] -> GCNConv(64) -> leaky -> GCNConv(32) -> leaky
// -> GCNConv(4) -> softmax.  N=100000, E=3200000.
// Round 16: r15 exposed k_linear1 at 95us with 24.8M LDS bank conflicts: both
// staging loops wrote with 64-float lane stride (bank step 0 -> 64-way conflict).
// Fix: Wt stride 64->68 (write step 4 banks, float4 reads stay aligned), xst
// stride 64->65 (reads stride-1 conflict-free). Nothing else changed.

#define BLK 256

// ---- Phase A: per-block LDS histogram over dst buckets (bucket = dst>>9) ----
__global__ __launch_bounds__(256) void k_hist(const int* __restrict__ dst,
                                              int* __restrict__ hist,
                                              int E, int CH, int NB) {
    __shared__ int h[256];
    int b = blockIdx.x, t = threadIdx.x;
    h[t] = 0;
    __syncthreads();
    int beg = b * CH, fin = min(E, beg + CH);
    for (int e = beg + t; e < fin; e += 256)
        atomicAdd(&h[dst[e] >> 9], 1);
    __syncthreads();
    if (t < NB) hist[t * 256 + b] = h[t];   // bucket-major layout
}

// ---- 3-kernel exclusive scan (n <= 512*256) ----
__global__ void k_scan1(const int* __restrict__ in, int* __restrict__ outv,
                        int* __restrict__ partials, int n) {
    __shared__ int sm[256];
    int i = blockIdx.x * 256 + threadIdx.x;
    int v = (i < n) ? in[i] : 0;
    sm[threadIdx.x] = v;
    __syncthreads();
    for (int off = 1; off < 256; off <<= 1) {
        int t = (threadIdx.x >= off) ? sm[threadIdx.x - off] : 0;
        __syncthreads();
        sm[threadIdx.x] += t;
        __syncthreads();
    }
    if (i < n) outv[i] = sm[threadIdx.x] - v;
    if (threadIdx.x == 255) partials[blockIdx.x] = sm[255];
}

__global__ void k_scan2(int* __restrict__ partials, int nb) {
    __shared__ int sm[512];
    int t = threadIdx.x;
    int v = (t < nb) ? partials[t] : 0;
    sm[t] = v;
    __syncthreads();
    for (int off = 1; off < 512; off <<= 1) {
        int x = (t >= off) ? sm[t - off] : 0;
        __syncthreads();
        sm[t] += x;
        __syncthreads();
    }
    if (t < nb) partials[t] = sm[t] - v;
}

__global__ void k_scan3(int* __restrict__ data, const int* __restrict__ partials, int n) {
    int i = blockIdx.x * 256 + threadIdx.x;
    if (i < n) data[i] += partials[i >> 8];
}

// ---- Phase C: scatter edges into bucket-sorted tmp ----
// record: x = (dlocal<<18) | src  (src < 2^18), y = w bits
__global__ __launch_bounds__(256) void k_bscatter(const int* __restrict__ src,
                                                  const int* __restrict__ dst,
                                                  const float* __restrict__ w,
                                                  const int* __restrict__ scanout,
                                                  int2* __restrict__ tmp,
                                                  int E, int CH, int NB) {
    __shared__ int cur[256];
    int b = blockIdx.x, t = threadIdx.x;
    if (t < NB) cur[t] = scanout[t * 256 + b];
    __syncthreads();
    int beg = b * CH, fin = min(E, beg + CH);
    for (int e = beg + t; e < fin; e += 256) {
        int d = dst[e];
        int q = d >> 9;
        int pos = atomicAdd(&cur[q], 1);             // LDS atomic
        tmp[pos] = make_int2(((d & 511) << 18) | src[e], __float_as_int(w[e]));
    }
}

// ---- Phase D: per-bucket CSR + fused dis = rsqrt(1 + sum_w) ----
__global__ __launch_bounds__(256) void k_bcsr(const int* __restrict__ scanout,
                                              const int2* __restrict__ tmp,
                                              int2* __restrict__ pack,
                                              int* __restrict__ row_ptr,
                                              float* __restrict__ dis,
                                              int n, int E, int NB) {
    __shared__ int cnt[512];
    __shared__ float wsum[512];
    __shared__ int psum[256];
    int q = blockIdx.x, t = threadIdx.x;
    int base = scanout[q * 256];
    int end  = (q == NB - 1) ? E : scanout[(q + 1) * 256];
    cnt[t] = 0; cnt[t + 256] = 0;
    wsum[t] = 0.f; wsum[t + 256] = 0.f;
    __syncthreads();
    for (int j = base + t; j < end; j += 256) {
        int2 r = tmp[j];
        int d = r.x >> 18;
        atomicAdd(&cnt[d], 1);
        atomicAdd(&wsum[d], __int_as_float(r.y));
    }
    __syncthreads();
    int a = cnt[2 * t], bb = cnt[2 * t + 1];
    psum[t] = a + bb;
    __syncthreads();
    for (int off = 1; off < 256; off <<= 1) {
        int v = (t >= off) ? psum[t - off] : 0;
        __syncthreads();
        psum[t] += v;
        __syncthreads();
    }
    int pex = psum[t] - (a + bb);
    __syncthreads();
    cnt[2 * t] = pex;                                // fill cursors
    cnt[2 * t + 1] = pex + a;
    int node0 = q * 512;
    if (node0 + 2 * t < n) {
        row_ptr[node0 + 2 * t] = base + pex;
        dis[node0 + 2 * t] = rsqrtf(1.f + wsum[2 * t]);
    }
    if (node0 + 2 * t + 1 < n) {
        row_ptr[node0 + 2 * t + 1] = base + pex + a;
        dis[node0 + 2 * t + 1] = rsqrtf(1.f + wsum[2 * t + 1]);
    }
    if (q == 0 && t == 0) row_ptr[n] = E;
    __syncthreads();
    for (int j = base + t; j < end; j += 256) {
        int2 r = tmp[j];
        int d = r.x >> 18;
        int pos = base + atomicAdd(&cnt[d], 1);      // LDS atomic
        pack[pos] = make_int2(r.x & 0x3FFFF, r.y);   // (src, w)
    }
}

// one wave per node: pack[j].y = dis[d] * w * dis[src]  (contiguous RMW, once)
__global__ __launch_bounds__(256) void k_norm(const int* __restrict__ rp,
                                              const float* __restrict__ dis,
                                              int2* __restrict__ pack, int n) {
    int node = blockIdx.x * 4 + (threadIdx.x >> 6);
    int lane = threadIdx.x & 63;
    if (node >= n) return;
    float dd = dis[node];
    int beg = rp[node], end = rp[node + 1];
    for (int j = beg + lane; j < end; j += 64) {
        int2 p = pack[j];
        p.y = __float_as_int(dd * __int_as_float(p.y) * dis[p.x]);
        pack[j] = p;
    }
}

__device__ __forceinline__ float leaky01(float v) {
    return v > 0.f ? v : 0.01f * v;
}
__device__ __forceinline__ float h2f(ushort u) {
    return __half2float(__ushort_as_half(u));
}
__device__ __forceinline__ ushort f2h(float f) {
    return __half_as_ushort(__float2half(f));
}
__device__ __forceinline__ float2 h2f2(uint u) {
    return make_float2(h2f((ushort)(u & 0xffff)), h2f((ushort)(u >> 16)));
}

// layer-1 linear x[N,128] @ W1.T -> h1 fp16 [N,64]. 64-node tile, 4 thr/node.
// LDS strides padded: Wt 68 (8-way max on one-time writes, aligned float4 reads),
// xst 65 (conflict-free reads, ~4-way one-time writes).
__global__ __launch_bounds__(256) void k_linear1(
        const float* __restrict__ in, const float* __restrict__ W,
        ushort* __restrict__ outh, int n) {
    constexpr int FIN = 128, FOUT = 64, TM = 64, CPT = 16;
    constexpr int WS = 68;             // padded Wt row stride
    constexpr int XS = TM + 1;         // 65, padded xst row stride
    __shared__ __align__(16) float Wt[FIN * WS];
    __shared__ __align__(16) float xst[FIN * XS];
    const int tid = threadIdx.x;
    const int nb = blockIdx.x * TM;

    // stage W transposed: i = c*128 + k (coalesced read), write Wt[k*WS + c]
    for (int i = tid; i < FIN * FOUT; i += 256) {
        int c = i >> 7, k = i & 127;
        Wt[k * WS + c] = W[i];
    }
    __syncthreads();
    for (int i4 = tid; i4 < TM * FIN / 4; i4 += 256) {
        int idx = i4 * 4;
        int r = idx >> 7, k0 = idx & 127;
        if (nb + r < n) {
            float4 v = *(const float4*)&in[(size_t)(nb + r) * FIN + k0];
            xst[(k0 + 0) * XS + r] = v.x;
            xst[(k0 + 1) * XS + r] = v.y;
            xst[(k0 + 2) * XS + r] = v.z;
            xst[(k0 + 3) * XS + r] = v.w;
        }
    }
    __syncthreads();

    const int nl = tid >> 2;
    const int c0 = (tid & 3) * CPT;
    if (nb + nl >= n) return;

    float4 acc[CPT / 4];
#pragma unroll
    for (int j = 0; j < CPT / 4; ++j) acc[j] = make_float4(0.f, 0.f, 0.f, 0.f);
#pragma unroll 8
    for (int k = 0; k < FIN; ++k) {
        float xv = xst[k * XS + nl];
        const float4* wr = (const float4*)&Wt[k * WS + c0];
#pragma unroll
        for (int j = 0; j < CPT / 4; ++j) {
            float4 w4 = wr[j];
            acc[j].x += xv * w4.x; acc[j].y += xv * w4.y;
            acc[j].z += xv * w4.z; acc[j].w += xv * w4.w;
        }
    }
    uint* o = (uint*)&outh[(size_t)(nb + nl) * FOUT + c0];
#pragma unroll
    for (int j = 0; j < CPT / 4; ++j) {
        float4 a = acc[j];
        o[2 * j + 0] = (uint)f2h(a.x) | ((uint)f2h(a.y) << 16);
        o[2 * j + 1] = (uint)f2h(a.z) | ((uint)f2h(a.w) << 16);
    }
}

// layer-1 agg + leaky(+b1) + W2 matmul -> h2 fp16 [N,32].  One wave per node;
// 8 edges per wave-instruction: 8-lane group es, lane g=l&7 loads uint4
// (16B = cols 8g..8g+7 of the fp16 row).
__global__ __launch_bounds__(256) void fgather64(
        const int* __restrict__ rp, const int2* __restrict__ pack,
        const float* __restrict__ dis, const ushort* __restrict__ h1h,
        const float* __restrict__ b1, const float* __restrict__ W2,   // [32][64]
        ushort* __restrict__ h2h, int n) {
    __shared__ float sW2t[64 * 33];    // [c][c2], padded
    __shared__ float sact[4][64];
    int tid = threadIdx.x;
    for (int i = tid; i < 2048; i += 256)
        sW2t[(i & 63) * 33 + (i >> 6)] = W2[i];
    int w = tid >> 6, l = tid & 63;
    int es = l >> 3, g = l & 7;        // edge-set 0..7, col group (cols 8g..8g+7)
    int node = blockIdx.x * 4 + w;
    bool valid = node < n;
    float acc[8] = {0.f, 0.f, 0.f, 0.f, 0.f, 0.f, 0.f, 0.f};
    if (valid) {
        int beg = rp[node], end = rp[node + 1];
        int j = beg;
        for (; j + 16 <= end; j += 16) {               // 16 edges in flight
            int2 pa = pack[j + es];
            int2 pb = pack[j + 8 + es];
            uint4 ua = *(const uint4*)&h1h[(size_t)pa.x * 64 + 8 * g];
            uint4 ub = *(const uint4*)&h1h[(size_t)pb.x * 64 + 8 * g];
            float na = __int_as_float(pa.y), nb2 = __int_as_float(pb.y);
            float2 v;
            v = h2f2(ua.x); acc[0] += na * v.x;  acc[1] += na * v.y;
            v = h2f2(ua.y); acc[2] += na * v.x;  acc[3] += na * v.y;
            v = h2f2(ua.z); acc[4] += na * v.x;  acc[5] += na * v.y;
            v = h2f2(ua.w); acc[6] += na * v.x;  acc[7] += na * v.y;
            v = h2f2(ub.x); acc[0] += nb2 * v.x; acc[1] += nb2 * v.y;
            v = h2f2(ub.y); acc[2] += nb2 * v.x; acc[3] += nb2 * v.y;
            v = h2f2(ub.z); acc[4] += nb2 * v.x; acc[5] += nb2 * v.y;
            v = h2f2(ub.w); acc[6] += nb2 * v.x; acc[7] += nb2 * v.y;
        }
        for (; j < end; j += 8) {
            if (j + es < end) {
                int2 p = pack[j + es];
                uint4 u = *(const uint4*)&h1h[(size_t)p.x * 64 + 8 * g];
                float nm = __int_as_float(p.y);
                float2 v;
                v = h2f2(u.x); acc[0] += nm * v.x; acc[1] += nm * v.y;
                v = h2f2(u.y); acc[2] += nm * v.x; acc[3] += nm * v.y;
                v = h2f2(u.z); acc[4] += nm * v.x; acc[5] += nm * v.y;
                v = h2f2(u.w); acc[6] += nm * v.x; acc[7] += nm * v.y;
            }
        }
        // combine the 8 edge-sets
#pragma unroll
        for (int u = 0; u < 8; ++u) {
            acc[u] += __shfl_xor(acc[u], 8);
            acc[u] += __shfl_xor(acc[u], 16);
            acc[u] += __shfl_xor(acc[u], 32);
        }
        if (es == 0) {                                  // self-loop + bias
            float dd = dis[node], d2 = dd * dd;
            uint4 u = *(const uint4*)&h1h[(size_t)node * 64 + 8 * g];
            float2 v;
            v = h2f2(u.x); acc[0] += d2 * v.x; acc[1] += d2 * v.y;
            v = h2f2(u.y); acc[2] += d2 * v.x; acc[3] += d2 * v.y;
            v = h2f2(u.z); acc[4] += d2 * v.x; acc[5] += d2 * v.y;
            v = h2f2(u.w); acc[6] += d2 * v.x; acc[7] += d2 * v.y;
#pragma unroll
            for (int u2 = 0; u2 < 8; ++u2)
                sact[w][8 * g + u2] = leaky01(acc[u2] + b1[8 * g + u2]);
        }
    }
    __syncthreads();
    if (valid) {
        int c2 = l & 31, half = l >> 5;
        float s = 0.f;
#pragma unroll 8
        for (int cc = 0; cc < 32; ++cc) {
            int c = half * 32 + cc;
            s += sW2t[c * 33 + c2] * sact[w][c];
        }
        s += __shfl_xor(s, 32);
        if (l < 32) h2h[(size_t)node * 32 + c2] = f2h(s);
    }
}

// layer-2 agg + leaky(+b2) + W3 matmul -> h3 f32 [N,4].  One wave per node;
// 8 edges/instr (8-lane groups x uint2 = cols 4g..4g+3), x2 unroll.
__global__ __launch_bounds__(256) void fgather32(
        const int* __restrict__ rp, const int2* __restrict__ pack,
        const float* __restrict__ dis, const ushort* __restrict__ h2h,
        const float* __restrict__ b2, const float* __restrict__ W3,   // [4][32]
        float* __restrict__ h3out, int n) {
    __shared__ float sW3t[32 * 5];     // [c][c3], padded
    __shared__ float sact[4][32];
    int tid = threadIdx.x;
    if (tid < 128) sW3t[(tid & 31) * 5 + (tid >> 5)] = W3[tid];
    int w = tid >> 6, l = tid & 63;
    int es = l >> 3, g = l & 7;        // cols 4g..4g+3
    int node = blockIdx.x * 4 + w;
    bool valid = node < n;
    float acc[4] = {0.f, 0.f, 0.f, 0.f};
    if (valid) {
        int beg = rp[node], end = rp[node + 1];
        int j = beg;
        for (; j + 16 <= end; j += 16) {               // 16 edges in flight
            int2 pa = pack[j + es];
            int2 pb = pack[j + 8 + es];
            uint2 ua = *(const uint2*)&h2h[(size_t)pa.x * 32 + 4 * g];
            uint2 ub = *(const uint2*)&h2h[(size_t)pb.x * 32 + 4 * g];
            float na = __int_as_float(pa.y), nb2 = __int_as_float(pb.y);
            float2 v;
            v = h2f2(ua.x); acc[0] += na * v.x;  acc[1] += na * v.y;
            v = h2f2(ua.y); acc[2] += na * v.x;  acc[3] += na * v.y;
            v = h2f2(ub.x); acc[0] += nb2 * v.x; acc[1] += nb2 * v.y;
            v = h2f2(ub.y); acc[2] += nb2 * v.x; acc[3] += nb2 * v.y;
        }
        for (; j < end; j += 8) {
            if (j + es < end) {
                int2 p = pack[j + es];
                uint2 u = *(const uint2*)&h2h[(size_t)p.x * 32 + 4 * g];
                float nm = __int_as_float(p.y);
                float2 v;
                v = h2f2(u.x); acc[0] += nm * v.x; acc[1] += nm * v.y;
                v = h2f2(u.y); acc[2] += nm * v.x; acc[3] += nm * v.y;
            }
        }
#pragma unroll
        for (int u = 0; u < 4; ++u) {
            acc[u] += __shfl_xor(acc[u], 8);
            acc[u] += __shfl_xor(acc[u], 16);
            acc[u] += __shfl_xor(acc[u], 32);
        }
        if (es == 0) {
            float dd = dis[node], d2 = dd * dd;
            uint2 u = *(const uint2*)&h2h[(size_t)node * 32 + 4 * g];
            float2 v;
            v = h2f2(u.x); acc[0] += d2 * v.x; acc[1] += d2 * v.y;
            v = h2f2(u.y); acc[2] += d2 * v.x; acc[3] += d2 * v.y;
#pragma unroll
            for (int u2 = 0; u2 < 4; ++u2)
                sact[w][4 * g + u2] = leaky01(acc[u2] + b2[4 * g + u2]);
        }
    }
    __syncthreads();
    if (valid && l < 32) {
        int c3 = l & 3;
        float s = 0.f;
#pragma unroll
        for (int m = 0; m < 4; ++m) {
            int c = (l >> 2) + 8 * m;
            s += sW3t[c * 5 + c3] * sact[w][c];
        }
        s += __shfl_xor(s, 4, 32);
        s += __shfl_xor(s, 8, 32);
        s += __shfl_xor(s, 16, 32);
        if (l < 4) h3out[(size_t)node * 4 + l] = s;
    }
}

// layer-3 agg + b3 + softmax -> out[N,4].  32-lane group per node; lane j owns
// edge beg+j and loads the full 16B h3 row as float4; xor-tree reduce.
__global__ __launch_bounds__(256) void fgather4(
        const int* __restrict__ rp, const int2* __restrict__ pack,
        const float* __restrict__ dis, const float* __restrict__ h3,
        const float* __restrict__ b3, float* __restrict__ out, int n) {
    int tid = threadIdx.x;
    int node = blockIdx.x * 8 + (tid >> 5);
    int l32 = tid & 31;
    if (node >= n) return;
    int beg = rp[node], end = rp[node + 1];
    float4 acc = make_float4(0.f, 0.f, 0.f, 0.f);
    for (int j = beg + l32; j < end; j += 32) {
        int2 p = pack[j];
        float4 hr = *(const float4*)&h3[(size_t)p.x * 4];
        float nm = __int_as_float(p.y);
        acc.x += nm * hr.x; acc.y += nm * hr.y;
        acc.z += nm * hr.z; acc.w += nm * hr.w;
    }
#pragma unroll
    for (int off = 1; off <= 16; off <<= 1) {
        acc.x += __shfl_xor(acc.x, off, 32);
        acc.y += __shfl_xor(acc.y, off, 32);
        acc.z += __shfl_xor(acc.z, off, 32);
        acc.w += __shfl_xor(acc.w, off, 32);
    }
    if (l32 == 0) {
        float dd = dis[node], d2 = dd * dd;
        float4 hr = *(const float4*)&h3[(size_t)node * 4];
        float v0 = acc.x + d2 * hr.x + b3[0];
        float v1 = acc.y + d2 * hr.y + b3[1];
        float v2 = acc.z + d2 * hr.z + b3[2];
        float v3 = acc.w + d2 * hr.w + b3[3];
        float m = fmaxf(fmaxf(v0, v1), fmaxf(v2, v3));
        float e0 = expf(v0 - m), e1 = expf(v1 - m);
        float e2 = expf(v2 - m), e3 = expf(v3 - m);
        float inv = 1.f / (e0 + e1 + e2 + e3);
        *(float4*)&out[(size_t)node * 4] =
            make_float4(e0 * inv, e1 * inv, e2 * inv, e3 * inv);
    }
}

static inline int cdiv(long long a, int b) { return (int)((a + b - 1) / b); }

extern "C" void kernel_launch(void* const* d_in, const int* in_sizes, int n_in,
                              void* d_out, int out_size, void* d_ws, size_t ws_size,
                              hipStream_t stream) {
    const float* x   = (const float*)d_in[0];
    const int*   ei  = (const int*)d_in[1];
    const float* ew  = (const float*)d_in[2];
    const float* W1  = (const float*)d_in[3];
    const float* b1  = (const float*)d_in[4];
    const float* W2  = (const float*)d_in[5];
    const float* b2  = (const float*)d_in[6];
    const float* W3  = (const float*)d_in[7];
    const float* b3  = (const float*)d_in[8];
    float* out = (float*)d_out;

    const int N = in_sizes[0] / 128;
    const int E = in_sizes[2];
    const int* src = ei;
    const int* dst = ei + E;

    const int NB = (N + 511) >> 9;          // buckets of 512 nodes
    const int GB = 256;
    const int CH = cdiv(E, GB);
    const int n_scan = NB * GB;

    char* base = (char*)d_ws;
    auto alloc = [&](size_t bytes) {
        char* p = base;
        base += (bytes + 255) & ~(size_t)255;
        return p;
    };
    float* dis      = (float*)alloc((size_t)N * 4);
    int*   row_ptr  = (int*)  alloc(((size_t)N + 1) * 4);
    int*   hist     = (int*)  alloc((size_t)n_scan * 4);
    int*   scanout  = (int*)  alloc((size_t)n_scan * 4);
    int*   partials = (int*)  alloc(512 * 4);
    int2*  pack     = (int2*) alloc((size_t)E * 8);
    char*  regA     = alloc((size_t)N * 64 * 4);   // tmp -> h1h(fp16) -> h3(f32)
    char*  regB     = alloc((size_t)N * 64 * 4);   // h2h (fp16)
    int2*   tmp = (int2*)regA;
    ushort* h1h = (ushort*)regA;
    float*  h3  = (float*)regA;                    // reuses regA after h1 dead
    ushort* h2h = (ushort*)regB;

    // --- CSR build via bucket sort; dis fused into k_bcsr; norm premult once ---
    k_hist<<<GB, 256, 0, stream>>>(dst, hist, E, CH, NB);
    k_scan1<<<cdiv(n_scan, 256), 256, 0, stream>>>(hist, scanout, partials, n_scan);
    k_scan2<<<1, 512, 0, stream>>>(partials, cdiv(n_scan, 256));
    k_scan3<<<cdiv(n_scan, 256), 256, 0, stream>>>(scanout, partials, n_scan);
    k_bscatter<<<GB, 256, 0, stream>>>(src, dst, ew, scanout, tmp, E, CH, NB);
    k_bcsr<<<NB, 256, 0, stream>>>(scanout, tmp, pack, row_ptr, dis, N, E, NB);
    k_norm<<<cdiv(N, 4), 256, 0, stream>>>(row_ptr, dis, pack, N);

    // --- fused layers (h1/h2 fp16, h3 f32) ---
    k_linear1<<<cdiv(N, 64), 256, 0, stream>>>(x, W1, h1h, N);
    fgather64<<<cdiv(N, 4), 256, 0, stream>>>(row_ptr, pack, dis, h1h, b1, W2, h2h, N);
    fgather32<<<cdiv(N, 4), 256, 0, stream>>>(row_ptr, pack, dis, h2h, b2, W3, h3, N);
    fgather4<<<cdiv(N, 8), 256, 0, stream>>>(row_ptr, pack, dis, h3, b3, out, N);
}

// Round 17
// 349.807 us; speedup vs baseline: 1.3259x; 1.0047x over previous
//
#include <hip/hip_runtime.h>
#include <hip/hip_fp16.h>

// GCN 3-layer forward: x[N,128] -> GCNConv(64) -> leaky -> GCNConv(32) -> leaky
// -> GCNConv(4) -> softmax.  N=100000, E=3200000.
// Round 17: fg64/fg32 gather loops software-pipelined (prefetch next iteration's
// pack records before current h-load wait; self-loop row issued before the loop).
// r16: fg64 90us, VALU 58%, FETCH 166MB -- co-limited by VALU and miss-path with
// imperfect overlap from the 2-level pack->h dependence.

#define BLK 256

// ---- Phase A: per-block LDS histogram over dst buckets (bucket = dst>>9) ----
__global__ __launch_bounds__(256) void k_hist(const int* __restrict__ dst,
                                              int* __restrict__ hist,
                                              int E, int CH, int NB) {
    __shared__ int h[256];
    int b = blockIdx.x, t = threadIdx.x;
    h[t] = 0;
    __syncthreads();
    int beg = b * CH, fin = min(E, beg + CH);
    for (int e = beg + t; e < fin; e += 256)
        atomicAdd(&h[dst[e] >> 9], 1);
    __syncthreads();
    if (t < NB) hist[t * 256 + b] = h[t];   // bucket-major layout
}

// ---- 3-kernel exclusive scan (n <= 512*256) ----
__global__ void k_scan1(const int* __restrict__ in, int* __restrict__ outv,
                        int* __restrict__ partials, int n) {
    __shared__ int sm[256];
    int i = blockIdx.x * 256 + threadIdx.x;
    int v = (i < n) ? in[i] : 0;
    sm[threadIdx.x] = v;
    __syncthreads();
    for (int off = 1; off < 256; off <<= 1) {
        int t = (threadIdx.x >= off) ? sm[threadIdx.x - off] : 0;
        __syncthreads();
        sm[threadIdx.x] += t;
        __syncthreads();
    }
    if (i < n) outv[i] = sm[threadIdx.x] - v;
    if (threadIdx.x == 255) partials[blockIdx.x] = sm[255];
}

__global__ void k_scan2(int* __restrict__ partials, int nb) {
    __shared__ int sm[512];
    int t = threadIdx.x;
    int v = (t < nb) ? partials[t] : 0;
    sm[t] = v;
    __syncthreads();
    for (int off = 1; off < 512; off <<= 1) {
        int x = (t >= off) ? sm[t - off] : 0;
        __syncthreads();
        sm[t] += x;
        __syncthreads();
    }
    if (t < nb) partials[t] = sm[t] - v;
}

__global__ void k_scan3(int* __restrict__ data, const int* __restrict__ partials, int n) {
    int i = blockIdx.x * 256 + threadIdx.x;
    if (i < n) data[i] += partials[i >> 8];
}

// ---- Phase C: scatter edges into bucket-sorted tmp ----
// record: x = (dlocal<<18) | src  (src < 2^18), y = w bits
__global__ __launch_bounds__(256) void k_bscatter(const int* __restrict__ src,
                                                  const int* __restrict__ dst,
                                                  const float* __restrict__ w,
                                                  const int* __restrict__ scanout,
                                                  int2* __restrict__ tmp,
                                                  int E, int CH, int NB) {
    __shared__ int cur[256];
    int b = blockIdx.x, t = threadIdx.x;
    if (t < NB) cur[t] = scanout[t * 256 + b];
    __syncthreads();
    int beg = b * CH, fin = min(E, beg + CH);
    for (int e = beg + t; e < fin; e += 256) {
        int d = dst[e];
        int q = d >> 9;
        int pos = atomicAdd(&cur[q], 1);             // LDS atomic
        tmp[pos] = make_int2(((d & 511) << 18) | src[e], __float_as_int(w[e]));
    }
}

// ---- Phase D: per-bucket CSR + fused dis = rsqrt(1 + sum_w) ----
__global__ __launch_bounds__(256) void k_bcsr(const int* __restrict__ scanout,
                                              const int2* __restrict__ tmp,
                                              int2* __restrict__ pack,
                                              int* __restrict__ row_ptr,
                                              float* __restrict__ dis,
                                              int n, int E, int NB) {
    __shared__ int cnt[512];
    __shared__ float wsum[512];
    __shared__ int psum[256];
    int q = blockIdx.x, t = threadIdx.x;
    int base = scanout[q * 256];
    int end  = (q == NB - 1) ? E : scanout[(q + 1) * 256];
    cnt[t] = 0; cnt[t + 256] = 0;
    wsum[t] = 0.f; wsum[t + 256] = 0.f;
    __syncthreads();
    for (int j = base + t; j < end; j += 256) {
        int2 r = tmp[j];
        int d = r.x >> 18;
        atomicAdd(&cnt[d], 1);
        atomicAdd(&wsum[d], __int_as_float(r.y));
    }
    __syncthreads();
    int a = cnt[2 * t], bb = cnt[2 * t + 1];
    psum[t] = a + bb;
    __syncthreads();
    for (int off = 1; off < 256; off <<= 1) {
        int v = (t >= off) ? psum[t - off] : 0;
        __syncthreads();
        psum[t] += v;
        __syncthreads();
    }
    int pex = psum[t] - (a + bb);
    __syncthreads();
    cnt[2 * t] = pex;                                // fill cursors
    cnt[2 * t + 1] = pex + a;
    int node0 = q * 512;
    if (node0 + 2 * t < n) {
        row_ptr[node0 + 2 * t] = base + pex;
        dis[node0 + 2 * t] = rsqrtf(1.f + wsum[2 * t]);
    }
    if (node0 + 2 * t + 1 < n) {
        row_ptr[node0 + 2 * t + 1] = base + pex + a;
        dis[node0 + 2 * t + 1] = rsqrtf(1.f + wsum[2 * t + 1]);
    }
    if (q == 0 && t == 0) row_ptr[n] = E;
    __syncthreads();
    for (int j = base + t; j < end; j += 256) {
        int2 r = tmp[j];
        int d = r.x >> 18;
        int pos = base + atomicAdd(&cnt[d], 1);      // LDS atomic
        pack[pos] = make_int2(r.x & 0x3FFFF, r.y);   // (src, w)
    }
}

// one wave per node: pack[j].y = dis[d] * w * dis[src]  (contiguous RMW, once)
__global__ __launch_bounds__(256) void k_norm(const int* __restrict__ rp,
                                              const float* __restrict__ dis,
                                              int2* __restrict__ pack, int n) {
    int node = blockIdx.x * 4 + (threadIdx.x >> 6);
    int lane = threadIdx.x & 63;
    if (node >= n) return;
    float dd = dis[node];
    int beg = rp[node], end = rp[node + 1];
    for (int j = beg + lane; j < end; j += 64) {
        int2 p = pack[j];
        p.y = __float_as_int(dd * __int_as_float(p.y) * dis[p.x]);
        pack[j] = p;
    }
}

__device__ __forceinline__ float leaky01(float v) {
    return v > 0.f ? v : 0.01f * v;
}
__device__ __forceinline__ float h2f(ushort u) {
    return __half2float(__ushort_as_half(u));
}
__device__ __forceinline__ ushort f2h(float f) {
    return __half_as_ushort(__float2half(f));
}
__device__ __forceinline__ float2 h2f2(uint u) {
    return make_float2(h2f((ushort)(u & 0xffff)), h2f((ushort)(u >> 16)));
}

// layer-1 linear x[N,128] @ W1.T -> h1 fp16 [N,64]. 64-node tile, 4 thr/node.
__global__ __launch_bounds__(256) void k_linear1(
        const float* __restrict__ in, const float* __restrict__ W,
        ushort* __restrict__ outh, int n) {
    constexpr int FIN = 128, FOUT = 64, TM = 64, CPT = 16;
    constexpr int WS = 68;             // padded Wt row stride
    constexpr int XS = TM + 1;         // 65, padded xst row stride
    __shared__ __align__(16) float Wt[FIN * WS];
    __shared__ __align__(16) float xst[FIN * XS];
    const int tid = threadIdx.x;
    const int nb = blockIdx.x * TM;

    for (int i = tid; i < FIN * FOUT; i += 256) {
        int c = i >> 7, k = i & 127;
        Wt[k * WS + c] = W[i];
    }
    __syncthreads();
    for (int i4 = tid; i4 < TM * FIN / 4; i4 += 256) {
        int idx = i4 * 4;
        int r = idx >> 7, k0 = idx & 127;
        if (nb + r < n) {
            float4 v = *(const float4*)&in[(size_t)(nb + r) * FIN + k0];
            xst[(k0 + 0) * XS + r] = v.x;
            xst[(k0 + 1) * XS + r] = v.y;
            xst[(k0 + 2) * XS + r] = v.z;
            xst[(k0 + 3) * XS + r] = v.w;
        }
    }
    __syncthreads();

    const int nl = tid >> 2;
    const int c0 = (tid & 3) * CPT;
    if (nb + nl >= n) return;

    float4 acc[CPT / 4];
#pragma unroll
    for (int j = 0; j < CPT / 4; ++j) acc[j] = make_float4(0.f, 0.f, 0.f, 0.f);
#pragma unroll 8
    for (int k = 0; k < FIN; ++k) {
        float xv = xst[k * XS + nl];
        const float4* wr = (const float4*)&Wt[k * WS + c0];
#pragma unroll
        for (int j = 0; j < CPT / 4; ++j) {
            float4 w4 = wr[j];
            acc[j].x += xv * w4.x; acc[j].y += xv * w4.y;
            acc[j].z += xv * w4.z; acc[j].w += xv * w4.w;
        }
    }
    uint* o = (uint*)&outh[(size_t)(nb + nl) * FOUT + c0];
#pragma unroll
    for (int j = 0; j < CPT / 4; ++j) {
        float4 a = acc[j];
        o[2 * j + 0] = (uint)f2h(a.x) | ((uint)f2h(a.y) << 16);
        o[2 * j + 1] = (uint)f2h(a.z) | ((uint)f2h(a.w) << 16);
    }
}

// layer-1 agg + leaky(+b1) + W2 matmul -> h2 fp16 [N,32].  One wave per node;
// 8-lane group es x uint4 = 8 edges/wave-instr; 2-stage pack prefetch pipeline.
__global__ __launch_bounds__(256) void fgather64(
        const int* __restrict__ rp, const int2* __restrict__ pack,
        const float* __restrict__ dis, const ushort* __restrict__ h1h,
        const float* __restrict__ b1, const float* __restrict__ W2,   // [32][64]
        ushort* __restrict__ h2h, int n) {
    __shared__ float sW2t[64 * 33];    // [c][c2], padded
    __shared__ float sact[4][64];
    int tid = threadIdx.x;
    for (int i = tid; i < 2048; i += 256)
        sW2t[(i & 63) * 33 + (i >> 6)] = W2[i];
    int w = tid >> 6, l = tid & 63;
    int es = l >> 3, g = l & 7;        // edge-set 0..7, col group (cols 8g..8g+7)
    int node = blockIdx.x * 4 + w;
    bool valid = node < n;
    float acc[8] = {0.f, 0.f, 0.f, 0.f, 0.f, 0.f, 0.f, 0.f};
    if (valid) {
        int beg = rp[node], end = rp[node + 1];
        // self-loop row: issue before the edge loop (independent)
        float d2 = 0.f;
        uint4 usf = make_uint4(0, 0, 0, 0);
        if (es == 0) {
            float dd = dis[node];
            d2 = dd * dd;
            usf = *(const uint4*)&h1h[(size_t)node * 64 + 8 * g];
        }
        int j = beg;
        bool have = (j + 16 <= end);
        int2 pa, pb;
        if (have) { pa = pack[j + es]; pb = pack[j + 8 + es]; }
        while (have) {
            int nj = j + 16;
            bool nhave = (nj + 16 <= end);
            int2 na, nb;
            if (nhave) { na = pack[nj + es]; nb = pack[nj + 8 + es]; }  // prefetch
            uint4 ua = *(const uint4*)&h1h[(size_t)pa.x * 64 + 8 * g];
            uint4 ub = *(const uint4*)&h1h[(size_t)pb.x * 64 + 8 * g];
            float na2 = __int_as_float(pa.y), nb2 = __int_as_float(pb.y);
            float2 v;
            v = h2f2(ua.x); acc[0] += na2 * v.x; acc[1] += na2 * v.y;
            v = h2f2(ua.y); acc[2] += na2 * v.x; acc[3] += na2 * v.y;
            v = h2f2(ua.z); acc[4] += na2 * v.x; acc[5] += na2 * v.y;
            v = h2f2(ua.w); acc[6] += na2 * v.x; acc[7] += na2 * v.y;
            v = h2f2(ub.x); acc[0] += nb2 * v.x; acc[1] += nb2 * v.y;
            v = h2f2(ub.y); acc[2] += nb2 * v.x; acc[3] += nb2 * v.y;
            v = h2f2(ub.z); acc[4] += nb2 * v.x; acc[5] += nb2 * v.y;
            v = h2f2(ub.w); acc[6] += nb2 * v.x; acc[7] += nb2 * v.y;
            j = nj; pa = na; pb = nb; have = nhave;
        }
        for (; j < end; j += 8) {
            if (j + es < end) {
                int2 p = pack[j + es];
                uint4 u = *(const uint4*)&h1h[(size_t)p.x * 64 + 8 * g];
                float nm = __int_as_float(p.y);
                float2 v;
                v = h2f2(u.x); acc[0] += nm * v.x; acc[1] += nm * v.y;
                v = h2f2(u.y); acc[2] += nm * v.x; acc[3] += nm * v.y;
                v = h2f2(u.z); acc[4] += nm * v.x; acc[5] += nm * v.y;
                v = h2f2(u.w); acc[6] += nm * v.x; acc[7] += nm * v.y;
            }
        }
#pragma unroll
        for (int u = 0; u < 8; ++u) {
            acc[u] += __shfl_xor(acc[u], 8);
            acc[u] += __shfl_xor(acc[u], 16);
            acc[u] += __shfl_xor(acc[u], 32);
        }
        if (es == 0) {                                  // self-loop + bias
            float2 v;
            v = h2f2(usf.x); acc[0] += d2 * v.x; acc[1] += d2 * v.y;
            v = h2f2(usf.y); acc[2] += d2 * v.x; acc[3] += d2 * v.y;
            v = h2f2(usf.z); acc[4] += d2 * v.x; acc[5] += d2 * v.y;
            v = h2f2(usf.w); acc[6] += d2 * v.x; acc[7] += d2 * v.y;
#pragma unroll
            for (int u2 = 0; u2 < 8; ++u2)
                sact[w][8 * g + u2] = leaky01(acc[u2] + b1[8 * g + u2]);
        }
    }
    __syncthreads();
    if (valid) {
        int c2 = l & 31, half = l >> 5;
        float s = 0.f;
#pragma unroll 8
        for (int cc = 0; cc < 32; ++cc) {
            int c = half * 32 + cc;
            s += sW2t[c * 33 + c2] * sact[w][c];
        }
        s += __shfl_xor(s, 32);
        if (l < 32) h2h[(size_t)node * 32 + c2] = f2h(s);
    }
}

// layer-2 agg + leaky(+b2) + W3 matmul -> h3 f32 [N,4].  One wave per node;
// 8-lane group es x uint2; 2-stage pack prefetch pipeline.
__global__ __launch_bounds__(256) void fgather32(
        const int* __restrict__ rp, const int2* __restrict__ pack,
        const float* __restrict__ dis, const ushort* __restrict__ h2h,
        const float* __restrict__ b2, const float* __restrict__ W3,   // [4][32]
        float* __restrict__ h3out, int n) {
    __shared__ float sW3t[32 * 5];     // [c][c3], padded
    __shared__ float sact[4][32];
    int tid = threadIdx.x;
    if (tid < 128) sW3t[(tid & 31) * 5 + (tid >> 5)] = W3[tid];
    int w = tid >> 6, l = tid & 63;
    int es = l >> 3, g = l & 7;        // cols 4g..4g+3
    int node = blockIdx.x * 4 + w;
    bool valid = node < n;
    float acc[4] = {0.f, 0.f, 0.f, 0.f};
    if (valid) {
        int beg = rp[node], end = rp[node + 1];
        float d2 = 0.f;
        uint2 usf = make_uint2(0, 0);
        if (es == 0) {
            float dd = dis[node];
            d2 = dd * dd;
            usf = *(const uint2*)&h2h[(size_t)node * 32 + 4 * g];
        }
        int j = beg;
        bool have = (j + 16 <= end);
        int2 pa, pb;
        if (have) { pa = pack[j + es]; pb = pack[j + 8 + es]; }
        while (have) {
            int nj = j + 16;
            bool nhave = (nj + 16 <= end);
            int2 na, nb;
            if (nhave) { na = pack[nj + es]; nb = pack[nj + 8 + es]; }
            uint2 ua = *(const uint2*)&h2h[(size_t)pa.x * 32 + 4 * g];
            uint2 ub = *(const uint2*)&h2h[(size_t)pb.x * 32 + 4 * g];
            float na2 = __int_as_float(pa.y), nb2 = __int_as_float(pb.y);
            float2 v;
            v = h2f2(ua.x); acc[0] += na2 * v.x; acc[1] += na2 * v.y;
            v = h2f2(ua.y); acc[2] += na2 * v.x; acc[3] += na2 * v.y;
            v = h2f2(ub.x); acc[0] += nb2 * v.x; acc[1] += nb2 * v.y;
            v = h2f2(ub.y); acc[2] += nb2 * v.x; acc[3] += nb2 * v.y;
            j = nj; pa = na; pb = nb; have = nhave;
        }
        for (; j < end; j += 8) {
            if (j + es < end) {
                int2 p = pack[j + es];
                uint2 u = *(const uint2*)&h2h[(size_t)p.x * 32 + 4 * g];
                float nm = __int_as_float(p.y);
                float2 v;
                v = h2f2(u.x); acc[0] += nm * v.x; acc[1] += nm * v.y;
                v = h2f2(u.y); acc[2] += nm * v.x; acc[3] += nm * v.y;
            }
        }
#pragma unroll
        for (int u = 0; u < 4; ++u) {
            acc[u] += __shfl_xor(acc[u], 8);
            acc[u] += __shfl_xor(acc[u], 16);
            acc[u] += __shfl_xor(acc[u], 32);
        }
        if (es == 0) {
            float2 v;
            v = h2f2(usf.x); acc[0] += d2 * v.x; acc[1] += d2 * v.y;
            v = h2f2(usf.y); acc[2] += d2 * v.x; acc[3] += d2 * v.y;
#pragma unroll
            for (int u2 = 0; u2 < 4; ++u2)
                sact[w][4 * g + u2] = leaky01(acc[u2] + b2[4 * g + u2]);
        }
    }
    __syncthreads();
    if (valid && l < 32) {
        int c3 = l & 3;
        float s = 0.f;
#pragma unroll
        for (int m = 0; m < 4; ++m) {
            int c = (l >> 2) + 8 * m;
            s += sW3t[c * 5 + c3] * sact[w][c];
        }
        s += __shfl_xor(s, 4, 32);
        s += __shfl_xor(s, 8, 32);
        s += __shfl_xor(s, 16, 32);
        if (l < 4) h3out[(size_t)node * 4 + l] = s;
    }
}

// layer-3 agg + b3 + softmax -> out[N,4].  32-lane group per node; lane j owns
// edge beg+j and loads the full 16B h3 row as float4; xor-tree reduce.
__global__ __launch_bounds__(256) void fgather4(
        const int* __restrict__ rp, const int2* __restrict__ pack,
        const float* __restrict__ dis, const float* __restrict__ h3,
        const float* __restrict__ b3, float* __restrict__ out, int n) {
    int tid = threadIdx.x;
    int node = blockIdx.x * 8 + (tid >> 5);
    int l32 = tid & 31;
    if (node >= n) return;
    int beg = rp[node], end = rp[node + 1];
    float4 acc = make_float4(0.f, 0.f, 0.f, 0.f);
    for (int j = beg + l32; j < end; j += 32) {
        int2 p = pack[j];
        float4 hr = *(const float4*)&h3[(size_t)p.x * 4];
        float nm = __int_as_float(p.y);
        acc.x += nm * hr.x; acc.y += nm * hr.y;
        acc.z += nm * hr.z; acc.w += nm * hr.w;
    }
#pragma unroll
    for (int off = 1; off <= 16; off <<= 1) {
        acc.x += __shfl_xor(acc.x, off, 32);
        acc.y += __shfl_xor(acc.y, off, 32);
        acc.z += __shfl_xor(acc.z, off, 32);
        acc.w += __shfl_xor(acc.w, off, 32);
    }
    if (l32 == 0) {
        float dd = dis[node], d2 = dd * dd;
        float4 hr = *(const float4*)&h3[(size_t)node * 4];
        float v0 = acc.x + d2 * hr.x + b3[0];
        float v1 = acc.y + d2 * hr.y + b3[1];
        float v2 = acc.z + d2 * hr.z + b3[2];
        float v3 = acc.w + d2 * hr.w + b3[3];
        float m = fmaxf(fmaxf(v0, v1), fmaxf(v2, v3));
        float e0 = expf(v0 - m), e1 = expf(v1 - m);
        float e2 = expf(v2 - m), e3 = expf(v3 - m);
        float inv = 1.f / (e0 + e1 + e2 + e3);
        *(float4*)&out[(size_t)node * 4] =
            make_float4(e0 * inv, e1 * inv, e2 * inv, e3 * inv);
    }
}

static inline int cdiv(long long a, int b) { return (int)((a + b - 1) / b); }

extern "C" void kernel_launch(void* const* d_in, const int* in_sizes, int n_in,
                              void* d_out, int out_size, void* d_ws, size_t ws_size,
                              hipStream_t stream) {
    const float* x   = (const float*)d_in[0];
    const int*   ei  = (const int*)d_in[1];
    const float* ew  = (const float*)d_in[2];
    const float* W1  = (const float*)d_in[3];
    const float* b1  = (const float*)d_in[4];
    const float* W2  = (const float*)d_in[5];
    const float* b2  = (const float*)d_in[6];
    const float* W3  = (const float*)d_in[7];
    const float* b3  = (const float*)d_in[8];
    float* out = (float*)d_out;

    const int N = in_sizes[0] / 128;
    const int E = in_sizes[2];
    const int* src = ei;
    const int* dst = ei + E;

    const int NB = (N + 511) >> 9;          // buckets of 512 nodes
    const int GB = 256;
    const int CH = cdiv(E, GB);
    const int n_scan = NB * GB;

    char* base = (char*)d_ws;
    auto alloc = [&](size_t bytes) {
        char* p = base;
        base += (bytes + 255) & ~(size_t)255;
        return p;
    };
    float* dis      = (float*)alloc((size_t)N * 4);
    int*   row_ptr  = (int*)  alloc(((size_t)N + 1) * 4);
    int*   hist     = (int*)  alloc((size_t)n_scan * 4);
    int*   scanout  = (int*)  alloc((size_t)n_scan * 4);
    int*   partials = (int*)  alloc(512 * 4);
    int2*  pack     = (int2*) alloc((size_t)E * 8);
    char*  regA     = alloc((size_t)N * 64 * 4);   // tmp -> h1h(fp16) -> h3(f32)
    char*  regB     = alloc((size_t)N * 64 * 4);   // h2h (fp16)
    int2*   tmp = (int2*)regA;
    ushort* h1h = (ushort*)regA;
    float*  h3  = (float*)regA;                    // reuses regA after h1 dead
    ushort* h2h = (ushort*)regB;

    // --- CSR build via bucket sort; dis fused into k_bcsr; norm premult once ---
    k_hist<<<GB, 256, 0, stream>>>(dst, hist, E, CH, NB);
    k_scan1<<<cdiv(n_scan, 256), 256, 0, stream>>>(hist, scanout, partials, n_scan);
    k_scan2<<<1, 512, 0, stream>>>(partials, cdiv(n_scan, 256));
    k_scan3<<<cdiv(n_scan, 256), 256, 0, stream>>>(scanout, partials, n_scan);
    k_bscatter<<<GB, 256, 0, stream>>>(src, dst, ew, scanout, tmp, E, CH, NB);
    k_bcsr<<<NB, 256, 0, stream>>>(scanout, tmp, pack, row_ptr, dis, N, E, NB);
    k_norm<<<cdiv(N, 4), 256, 0, stream>>>(row_ptr, dis, pack, N);

    // --- fused layers (h1/h2 fp16, h3 f32) ---
    k_linear1<<<cdiv(N, 64), 256, 0, stream>>>(x, W1, h1h, N);
    fgather64<<<cdiv(N, 4), 256, 0, stream>>>(row_ptr, pack, dis, h1h, b1, W2, h2h, N);
    fgather32<<<cdiv(N, 4), 256, 0, stream>>>(row_ptr, pack, dis, h2h, b2, W3, h3, N);
    fgather4<<<cdiv(N, 8), 256, 0, stream>>>(row_ptr, pack, dis, h3, b3, out, N);
}